// Round 8
// baseline (391.622 us; speedup 1.0000x reference)
//
#include <hip/hip_runtime.h>
#include <hip/hip_bf16.h>
#include <math.h>

#define B_    4
#define T_    1536
#define DIN_  512
#define D_    512
#define K_    2
#define H_    8
#define BAND_ 24
#define DH_   64
#define M_    (B_*T_)      // 6144 rows
#define M2_   (2*M_)       // both streams batched
#define ALPHA_ 6.0f
#define BETA_  0.5f
#define EPS_   1e-5f

using bf8  = __attribute__((ext_vector_type(8))) short;   // 8 bf16 (4 VGPRs)
using f32x4 = __attribute__((ext_vector_type(4))) float;  // 4 fp32 acc

__device__ __forceinline__ void async_copy16(const void* g, void* l) {
  __builtin_amdgcn_global_load_lds(
      (const __attribute__((address_space(1))) unsigned int*)g,
      (__attribute__((address_space(3))) unsigned int*)l, 16, 0, 0);
}

__device__ __forceinline__ short f2bf(float v) {
  __hip_bfloat16 h = (__hip_bfloat16)v;
  return *(short*)&h;
}
__device__ __forceinline__ float bf2f(short s) {
  union { unsigned u; float f; } c;
  c.u = ((unsigned)(unsigned short)s) << 16;
  return c.f;
}
// XOR-swizzle of 16B chunks within each 64-element column block (bank-conflict fix)
__device__ __forceinline__ int swz64(int row, int col) {
  return (col & ~63) | ((((col >> 3) ^ row) & 7) << 3) | (col & 7);
}
// tanh-form gelu: max abs err ~1e-3; one v_exp + one v_rcp
__device__ __forceinline__ float fast_gelu(float x) {
  const float y = x * fmaf(0.0356774081f, x * x, 0.7978845608f);
  const float e = __expf(2.0f * y);
  const float t = fmaf(-2.0f, __frcp_rn(e + 1.0f), 1.0f);   // tanh(y)
  return 0.5f * x * (1.0f + t);
}

// ---------------- bf16 MFMA GEMM: C = A[M,Kd] @ Bt[N,Kd]^T + bias (+res) (+gelu)
// A and Bt chunk-swizzled. flags: 1=fast-gelu, 2=bf16 out, 4=swizzled bf16 out, 8=res is bf16.
// 1-D grid, XCD-aware remap (requires gy % 8 == 0).
template<int BM, int BN, int NI, int NJ>
__global__ __launch_bounds__(256) void gemm_bt_t(
    const short* __restrict__ A, const short* __restrict__ Bt,
    const float* __restrict__ bias, const void* __restrict__ res,
    void* __restrict__ Cout, int M, int N, int Kd, int flags, int gx) {
  __shared__ short lA[BM * 64];
  __shared__ short lB[BN * 64];
  const int gy   = gridDim.x / gx;
  const int xcd  = blockIdx.x & 7;
  const int seq  = blockIdx.x >> 3;
  const int rpx  = gy >> 3;                 // row-tiles per XCD
  const int by   = xcd * rpx + seq / gx;
  const int bx   = seq % gx;
  const int tid  = threadIdx.x;
  const int wave = tid >> 6, lane = tid & 63;
  const int block_m = by * BM, block_n = bx * BN;
  const int wm = (wave & 1) * (BM / 2), wn = (wave >> 1) * (BN / 2);
  const int l15 = lane & 15, quad = lane >> 4, l7 = lane & 7;
  f32x4 acc[NI][NJ] = {};

  for (int k0 = 0; k0 < Kd; k0 += 64) {
    __syncthreads();               // previous tile's LDS reads complete
#pragma unroll
    for (int i = 0; i < BM / 32; ++i) {
      const int cb = wave * (BM * 2) + i * 64;
      const int c  = cb + lane;                 // chunk of 8 bf16
      async_copy16(A + (size_t)(block_m + (c >> 3)) * Kd + k0 + (c & 7) * 8,
                   &lA[cb * 8]);
    }
#pragma unroll
    for (int i = 0; i < BN / 32; ++i) {
      const int cb = wave * (BN * 2) + i * 64;
      const int c  = cb + lane;
      async_copy16(Bt + (size_t)(block_n + (c >> 3)) * Kd + k0 + (c & 7) * 8,
                   &lB[cb * 8]);
    }
    __syncthreads();               // barrier drains vmcnt => LDS tiles ready
#pragma unroll
    for (int ks = 0; ks < 2; ++ks) {
      bf8 af[NI], bfr[NJ];
#pragma unroll
      for (int i = 0; i < NI; ++i)
        af[i] = *(const bf8*)&lA[(wm + i * 16 + l15) * 64 + (((ks * 4 + quad) ^ l7) << 3)];
#pragma unroll
      for (int j = 0; j < NJ; ++j)
        bfr[j] = *(const bf8*)&lB[(wn + j * 16 + l15) * 64 + (((ks * 4 + quad) ^ l7) << 3)];
#pragma unroll
      for (int i = 0; i < NI; ++i)
#pragma unroll
        for (int j = 0; j < NJ; ++j)
          acc[i][j] = __builtin_amdgcn_mfma_f32_16x16x32_bf16(af[i], bfr[j], acc[i][j], 0, 0, 0);
    }
  }

  const int do_gelu = flags & 1, out_bf = flags & 2, out_sw = flags & 4, res_bf = flags & 8;
#pragma unroll
  for (int i = 0; i < NI; ++i) {
    const int mbase = block_m + wm + i * 16 + (lane >> 4) * 4;
#pragma unroll
    for (int j = 0; j < NJ; ++j) {
      const int col = block_n + wn + j * 16 + l15;
      const float bb = bias[col];
#pragma unroll
      for (int r = 0; r < 4; ++r) {
        const int row = mbase + r;
        const size_t idx = (size_t)row * N + col;
        float v = acc[i][j][r] + bb;
        if (res) v += res_bf ? bf2f(((const short*)res)[idx]) : ((const float*)res)[idx];
        if (do_gelu) v = fast_gelu(v);
        if (out_bf) {
          const int oc = out_sw ? swz64(row, col) : col;
          ((short*)Cout)[(size_t)row * N + oc] = f2bf(v);
        } else {
          ((float*)Cout)[idx] = v;
        }
      }
    }
  }
}

// ---------------- transpose + convert: W[K,N] fp32 -> Wt[N,K] bf16 (chunk-swizzled)
__global__ __launch_bounds__(256) void tconv_k(const float* __restrict__ W,
                                               short* __restrict__ Wt, int K, int N) {
  __shared__ float s[32][33];
  const int tx = threadIdx.x & 31, ty = threadIdx.x >> 5;  // ty 0..7
  const int k0 = blockIdx.y * 32, n0 = blockIdx.x * 32;
#pragma unroll
  for (int r = 0; r < 4; ++r)
    s[ty * 4 + r][tx] = W[(size_t)(k0 + ty * 4 + r) * N + n0 + tx];
  __syncthreads();
#pragma unroll
  for (int r = 0; r < 4; ++r) {
    const int n = n0 + ty * 4 + r;
    Wt[(size_t)n * K + swz64(n, k0 + tx)] = f2bf(s[tx][ty * 4 + r]);
  }
}

// ---------------- fp32 -> bf16 elementwise (chunk-swizzled, width 512)
__global__ void cvt_k(const float* __restrict__ x, short* __restrict__ y, int n) {
  const int i = blockIdx.x * blockDim.x + threadIdx.x;
  if (i < n) {
    const int row = i >> 9, col = i & 511;
    y[((size_t)row << 9) | swz64(row, col)] = f2bf(x[i]);
  }
}

// ---------------- concat two bias vectors [n]+[n] -> [2n]
__global__ void concat2_k(const float* __restrict__ a, const float* __restrict__ b,
                          float* __restrict__ o, int n) {
  const int i = blockIdx.x * blockDim.x + threadIdx.x;
  if (i < n) o[i] = a[i];
  else if (i < 2 * n) o[i] = b[i - n];
}

// ---------------- block reduction helper (256 threads)
__device__ __forceinline__ float block_sum(float s, float* red, int tid) {
  red[tid] = s; __syncthreads();
  for (int o = 128; o > 0; o >>= 1) {
    if (tid < o) red[tid] += red[tid + o];
    __syncthreads();
  }
  float r = red[0];
  __syncthreads();
  return r;
}

// ---------------- LayerNorm, bf16 in: out(bf16, swizzled) = LN(in) * g + b
__global__ __launch_bounds__(256) void ln_bf_k(const short* __restrict__ in,
                                               const float* __restrict__ g,
                                               const float* __restrict__ b,
                                               short* __restrict__ out) {
  __shared__ float red[256];
  const int row = blockIdx.x, tid = threadIdx.x;
  const short2 xv = *(const short2*)&in[(size_t)row * D_ + 2 * tid];
  const float v0 = bf2f(xv.x), v1 = bf2f(xv.y);
  const float mean = block_sum(v0 + v1, red, tid) * (1.0f / D_);
  const float d0 = v0 - mean, d1 = v1 - mean;
  const float var = block_sum(d0 * d0 + d1 * d1, red, tid) * (1.0f / D_);
  const float inv = rsqrtf(var + EPS_);
  const float2 gg = *(const float2*)&g[2 * tid];
  const float2 bb = *(const float2*)&b[2 * tid];
  short2 o;
  o.x = f2bf(d0 * inv * gg.x + bb.x);
  o.y = f2bf(d1 * inv * gg.y + bb.y);
  *(short2*)&out[(size_t)row * D_ + swz64(row, 2 * tid)] = o;
}

// ---------------- gate + LN, both streams (X bf16 in): Xk(bf16) ; LN out swizzled bf16
__global__ __launch_bounds__(256) void scale_ln_k(
    const short* __restrict__ X, const float* __restrict__ Ain,
    const float* __restrict__ g, const float* __restrict__ b,
    short* __restrict__ Xk, short* __restrict__ out) {
  __shared__ float red[256];
  const int row = blockIdx.x, tid = threadIdx.x;
  const int kk = row / M_, rm = row % M_;
  const float a = Ain[(size_t)rm * K_ + kk];
  const float w = 1.0f / (1.0f + __expf(-ALPHA_ * (a - BETA_)));
  const short2 xv = *(const short2*)&X[(size_t)rm * D_ + 2 * tid];
  const float v0 = bf2f(xv.x) * w, v1 = bf2f(xv.y) * w;
  short2 xo; xo.x = f2bf(v0); xo.y = f2bf(v1);
  *(short2*)&Xk[(size_t)row * D_ + 2 * tid] = xo;
  const float mean = block_sum(v0 + v1, red, tid) * (1.0f / D_);
  const float d0 = v0 - mean, d1 = v1 - mean;
  const float var = block_sum(d0 * d0 + d1 * d1, red, tid) * (1.0f / D_);
  const float inv = rsqrtf(var + EPS_);
  const float2 gg = *(const float2*)&g[2 * tid];
  const float2 bb = *(const float2*)&b[2 * tid];
  short2 o;
  o.x = f2bf(d0 * inv * gg.x + bb.x);
  o.y = f2bf(d1 * inv * gg.y + bb.y);
  *(short2*)&out[(size_t)row * D_ + swz64(row, 2 * tid)] = o;
}

// ---------------- final LN: in = T2 (y+h2, fp32) + tag; scatter to concat layout
__global__ __launch_bounds__(256) void final_ln_k(
    const float* __restrict__ t2, const float* __restrict__ tags,
    const float* __restrict__ g, const float* __restrict__ b,
    float* __restrict__ out) {
  __shared__ float red[256];
  const int row = blockIdx.x, tid = threadIdx.x;
  const int kk = row / M_, rm = row % M_;
  const int bb = rm / T_, t = rm % T_;
  const size_t orow = (size_t)bb * (K_ * T_) + (size_t)kk * T_ + t;
  const float v0 = t2[(size_t)row * D_ + tid]       + tags[(size_t)kk * D_ + tid];
  const float v1 = t2[(size_t)row * D_ + tid + 256] + tags[(size_t)kk * D_ + tid + 256];
  const float mean = block_sum(v0 + v1, red, tid) * (1.0f / D_);
  const float d0 = v0 - mean, d1 = v1 - mean;
  const float var = block_sum(d0 * d0 + d1 * d1, red, tid) * (1.0f / D_);
  const float inv = rsqrtf(var + EPS_);
  out[orow * D_ + tid]       = d0 * inv * g[tid]       + b[tid];
  out[orow * D_ + tid + 256] = d1 * inv * g[tid + 256] + b[tid + 256];
}

// ---------------- MFMA banded attention, both streams
// q [2M,D] bf16 (unswizzled); KVp [M,2D] bf16 (unswizzled); out bf16 swizzled
#define QT_  64
#define KT_  (QT_ + 2 * BAND_)   // 112 rows
#define SKQ_ 72                  // row stride (shorts) for sK/sQ/sP
#define STV_ 136                 // row stride (shorts) for sVt
__global__ __launch_bounds__(256) void attn_mfma_k(
    const short* __restrict__ q, const short* __restrict__ KVp,
    short* __restrict__ out) {
  __shared__ short sK[KT_ * SKQ_];
  __shared__ short sQ[QT_ * SKQ_];
  __shared__ short sVt[DH_ * STV_];     // transposed: [dim][key row]
  __shared__ short sP[4][16 * SKQ_];
  const int t0 = blockIdx.x * QT_;
  const int h  = blockIdx.y;
  const int z  = blockIdx.z;            // kk*B + b
  const int b  = z % B_;
  const int tid = threadIdx.x;
  const int wave = tid >> 6, lane = tid & 63;
  const int rr = tid >> 5, c2 = tid & 31;

  for (int r0 = 0; r0 < KT_; r0 += 8) {
    const int r = r0 + rr;
    const int s = t0 - BAND_ + r;
    short2 kv = {0, 0}, vv = {0, 0};
    if (s >= 0 && s < T_) {
      const size_t g = (size_t)(b * T_ + s) * (2 * D_) + h * DH_ + c2 * 2;
      kv = *(const short2*)&KVp[g];
      vv = *(const short2*)&KVp[g + D_];
    }
    *(short2*)&sK[r * SKQ_ + c2 * 2] = kv;
    sVt[(c2 * 2)     * STV_ + r] = vv.x;
    sVt[(c2 * 2 + 1) * STV_ + r] = vv.y;
  }
  for (int r0 = 0; r0 < QT_; r0 += 8) {
    const int r = r0 + rr;
    const size_t g = (size_t)(z * T_ + t0 + r) * D_ + h * DH_ + c2 * 2;
    *(short2*)&sQ[r * SKQ_ + c2 * 2] = *(const short2*)&q[g];
  }
  __syncthreads();

  const int qg  = wave * 16;            // query group base (also key window base)
  const int l15 = lane & 15, quad = lane >> 4;

  // ---- S = Q16x64 @ K64x64^T  (8 MFMAs)
  bf8 qa0 = *(const bf8*)&sQ[(qg + l15) * SKQ_ + quad * 8];
  bf8 qa1 = *(const bf8*)&sQ[(qg + l15) * SKQ_ + 32 + quad * 8];
  f32x4 acc[4];
#pragma unroll
  for (int j = 0; j < 4; ++j) {
    const bf8 kb0 = *(const bf8*)&sK[(qg + j * 16 + l15) * SKQ_ + quad * 8];
    const bf8 kb1 = *(const bf8*)&sK[(qg + j * 16 + l15) * SKQ_ + 32 + quad * 8];
    f32x4 z4 = {0.f, 0.f, 0.f, 0.f};
    acc[j] = __builtin_amdgcn_mfma_f32_16x16x32_bf16(qa0, kb0, z4, 0, 0, 0);
    acc[j] = __builtin_amdgcn_mfma_f32_16x16x32_bf16(qa1, kb1, acc[j], 0, 0, 0);
  }

  // ---- banded softmax on C-layout rows (row = quad*4+reg, col = j*16+l15)
#pragma unroll
  for (int reg = 0; reg < 4; ++reg) {
    const int i = quad * 4 + reg;       // query within group
    float sc[4];
    float mx = -1e30f;
#pragma unroll
    for (int j = 0; j < 4; ++j) {
      const int c = j * 16 + l15;       // key within 64-window
      const int s = t0 + qg - BAND_ + c;
      const int rel = c - i;            // in [0,48] when inside band
      const bool valid = (rel >= 0) && (rel <= 2 * BAND_) && (s >= 0) && (s < T_);
      sc[j] = valid ? acc[j][reg] * 0.125f : -1e30f;
      mx = fmaxf(mx, sc[j]);
    }
    for (int o = 1; o < 16; o <<= 1) mx = fmaxf(mx, __shfl_xor(mx, o));
    float p[4], se = 0.0f;
#pragma unroll
    for (int j = 0; j < 4; ++j) {
      p[j] = (sc[j] > -1e29f) ? __expf(sc[j] - mx) : 0.0f;
      se += p[j];
    }
    for (int o = 1; o < 16; o <<= 1) se += __shfl_xor(se, o);
    const float inv = 1.0f / se;
#pragma unroll
    for (int j = 0; j < 4; ++j)
      sP[wave][i * SKQ_ + j * 16 + l15] = f2bf(p[j] * inv);
  }

  // ---- O = P16x64 @ V64x64  (8 MFMAs; V from transposed LDS)
  const bf8 pa0 = *(const bf8*)&sP[wave][l15 * SKQ_ + quad * 8];
  const bf8 pa1 = *(const bf8*)&sP[wave][l15 * SKQ_ + 32 + quad * 8];
  f32x4 oacc[4] = {};
#pragma unroll
  for (int dt = 0; dt < 4; ++dt) {
    const bf8 vb0 = *(const bf8*)&sVt[(dt * 16 + l15) * STV_ + qg + quad * 8];
    const bf8 vb1 = *(const bf8*)&sVt[(dt * 16 + l15) * STV_ + qg + 32 + quad * 8];
    oacc[dt] = __builtin_amdgcn_mfma_f32_16x16x32_bf16(pa0, vb0, oacc[dt], 0, 0, 0);
    oacc[dt] = __builtin_amdgcn_mfma_f32_16x16x32_bf16(pa1, vb1, oacc[dt], 0, 0, 0);
  }
#pragma unroll
  for (int dt = 0; dt < 4; ++dt)
#pragma unroll
    for (int reg = 0; reg < 4; ++reg) {
      const int i = quad * 4 + reg;
      const int row = t0 + qg + i;
      const int col = h * DH_ + dt * 16 + l15;
      out[(size_t)(z * T_ + row) * D_ + swz64(row, col)] = f2bf(oacc[dt][reg]);
    }
}

extern "C" void kernel_launch(void* const* d_in, const int* in_sizes, int n_in,
                              void* d_out, int out_size, void* d_ws, size_t ws_size,
                              hipStream_t stream) {
  const float* x_m    = (const float*)d_in[0];
  const float* A      = (const float*)d_in[1];
  const float* W_in   = (const float*)d_in[2];
  const float* b_in   = (const float*)d_in[3];
  const float* ln_q_g = (const float*)d_in[4];
  const float* ln_q_b = (const float*)d_in[5];
  const float* ln_kv_g= (const float*)d_in[6];
  const float* ln_kv_b= (const float*)d_in[7];
  const float* Wq     = (const float*)d_in[8];
  const float* bq     = (const float*)d_in[9];
  const float* Wk     = (const float*)d_in[10];
  const float* bk     = (const float*)d_in[11];
  const float* Wv     = (const float*)d_in[12];
  const float* bv     = (const float*)d_in[13];
  const float* Wo     = (const float*)d_in[14];
  const float* bo     = (const float*)d_in[15];
  const float* ln_f_g = (const float*)d_in[16];
  const float* ln_f_b = (const float*)d_in[17];
  const float* W1     = (const float*)d_in[18];
  const float* b1     = (const float*)d_in[19];
  const float* W2     = (const float*)d_in[20];
  const float* b2     = (const float*)d_in[21];
  const float* ln_s_g = (const float*)d_in[22];
  const float* ln_s_b = (const float*)d_in[23];
  const float* tags   = (const float*)d_in[24];
  float* out = (float*)d_out;

  const size_t MD = (size_t)M_ * D_;
  // fp32 buffers
  float* T2  = (float*)d_ws;           // [2M,D]  y + h2
  float* bkv = T2 + 2 * MD;            // [1024]
  // bf16 buffers
  short* X    = (short*)(bkv + 1024);  // [M,D]  unswizzled
  short* Xk2  = X    + MD;             // [2M,D] gated X, then y (bf16, unswizzled)
  short* LNb2 = Xk2  + 2 * MD;         // [2M,D]; first MD also = KV LN (swizzled)
  short* qb2  = LNb2 + 2 * MD;         // [2M,D]; first MD also = xb (x_m bf16 swz)
  short* KVpb = qb2  + 2 * MD;         // [M,2D] interleaved K|V (unswizzled)
  short* H1b  = KVpb + 2 * MD;         // [2M,4D] swizzled
  short* WtIn = H1b + (size_t)M2_ * 4 * D_;
  short* WtQ  = WtIn + (size_t)D_ * DIN_;
  short* WtKV = WtQ  + (size_t)D_ * D_;        // [2D, D]
  short* WtO  = WtKV + (size_t)2 * D_ * D_;
  short* Wt1  = WtO  + (size_t)D_ * D_;        // [4D, D]
  short* Wt2  = Wt1  + (size_t)4 * D_ * D_;    // [D, 4D]
  short* xb   = qb2;                   // alias (used before Q GEMM)
  short* KVb  = LNb2;                  // alias (used before scale_ln)

  // ---- prep: weights to bf16 [N,K] swizzled, x_m to bf16 swizzled, concat K/V bias
  cvt_k<<<(M_ * DIN_ + 255) / 256, 256, 0, stream>>>(x_m, xb, M_ * DIN_);
  concat2_k<<<4, 256, 0, stream>>>(bk, bv, bkv, D_);
  tconv_k<<<dim3(D_/32,    DIN_/32),  256, 0, stream>>>(W_in, WtIn, DIN_, D_);
  tconv_k<<<dim3(D_/32,    D_/32),    256, 0, stream>>>(Wq,   WtQ,  D_,   D_);
  tconv_k<<<dim3(D_/32,    D_/32),    256, 0, stream>>>(Wk,   WtKV, D_,   D_);
  tconv_k<<<dim3(D_/32,    D_/32),    256, 0, stream>>>(Wv,   WtKV + (size_t)D_*D_, D_, D_);
  tconv_k<<<dim3(D_/32,    D_/32),    256, 0, stream>>>(Wo,   WtO,  D_,   D_);
  tconv_k<<<dim3((4*D_)/32, D_/32),   256, 0, stream>>>(W1,   Wt1,  D_,   4*D_);
  tconv_k<<<dim3(D_/32,  (4*D_)/32),  256, 0, stream>>>(W2,   Wt2,  4*D_, D_);

  // X = x_m @ W_in + b_in  (bf16 unswizzled out)
  gemm_bt_t<128,64,4,2><<<(D_/64) * (M_/128), 256, 0, stream>>>(
      xb, WtIn, b_in, nullptr, X, M_, D_, DIN_, 2, D_/64);
  // KVb = LN(X)  (swizzled bf16)
  ln_bf_k<<<M_, 256, 0, stream>>>(X, ln_kv_g, ln_kv_b, KVb);
  // K|V projection, N=1024 (bf16 out, UNswizzled: consumed by attention)
  gemm_bt_t<128,128,4,4><<<((2*D_)/128) * (M_/128), 256, 0, stream>>>(
      KVb, WtKV, bkv, nullptr, KVpb, M_, 2*D_, D_, 2, (2*D_)/128);

  // ---- both streams batched over 2M rows
  scale_ln_k<<<M2_, 256, 0, stream>>>(X, A, ln_q_g, ln_q_b, Xk2, LNb2);
  gemm_bt_t<128,128,4,4><<<(D_/128) * (M2_/128), 256, 0, stream>>>(
      LNb2, WtQ, bq, nullptr, qb2, M2_, D_, D_, 2, D_/128);  // q: unswizzled
  attn_mfma_k<<<dim3(T_/QT_, H_, B_*K_), 256, 0, stream>>>(qb2, KVpb, LNb2);
  // y = attn @ Wo + bo + Xk  (bf16 in-place, res bf16)
  gemm_bt_t<128,128,4,4><<<(D_/128) * (M2_/128), 256, 0, stream>>>(
      LNb2, WtO, bo, Xk2, Xk2, M2_, D_, D_, 2 | 8, D_/128);
  ln_bf_k<<<M2_, 256, 0, stream>>>(Xk2, ln_f_g, ln_f_b, LNb2);
  gemm_bt_t<128,128,4,4><<<((4*D_)/128) * (M2_/128), 256, 0, stream>>>(
      LNb2, Wt1, b1, nullptr, H1b, M2_, 4*D_, D_, 1 | 2 | 4, (4*D_)/128);
  // T2 = h1 @ W2 + b2 + y  (fp32 out, res bf16)
  gemm_bt_t<128,64,4,2><<<(D_/64) * (M2_/128), 256, 0, stream>>>(
      H1b, Wt2, b2, Xk2, T2, M2_, D_, 4*D_, 8, D_/64);
  final_ln_k<<<M2_, 256, 0, stream>>>(T2, tags, ln_s_g, ln_s_b, out);
}

// Round 9
// 384.196 us; speedup vs baseline: 1.0193x; 1.0193x over previous
//
#include <hip/hip_runtime.h>
#include <hip/hip_bf16.h>
#include <math.h>

#define B_    4
#define T_    1536
#define DIN_  512
#define D_    512
#define K_    2
#define H_    8
#define BAND_ 24
#define DH_   64
#define M_    (B_*T_)      // 6144 rows
#define M2_   (2*M_)       // both streams batched
#define ALPHA_ 6.0f
#define BETA_  0.5f
#define EPS_   1e-5f

using bf8  = __attribute__((ext_vector_type(8))) short;   // 8 bf16 (4 VGPRs)
using f32x4 = __attribute__((ext_vector_type(4))) float;  // 4 fp32 acc

__device__ __forceinline__ void async_copy16(const void* g, void* l) {
  __builtin_amdgcn_global_load_lds(
      (const __attribute__((address_space(1))) unsigned int*)g,
      (__attribute__((address_space(3))) unsigned int*)l, 16, 0, 0);
}

__device__ __forceinline__ short f2bf(float v) {
  __hip_bfloat16 h = (__hip_bfloat16)v;
  return *(short*)&h;
}
__device__ __forceinline__ float bf2f(short s) {
  union { unsigned u; float f; } c;
  c.u = ((unsigned)(unsigned short)s) << 16;
  return c.f;
}
// XOR-swizzle of 16B chunks within each 64-element column block (bank-conflict fix)
__device__ __forceinline__ int swz64(int row, int col) {
  return (col & ~63) | ((((col >> 3) ^ row) & 7) << 3) | (col & 7);
}
// tanh-form gelu, raw HW transcendentals: 8 VALU, no div expansion, no branches.
// tanh(u)=1-2/(1+e^{2u}) => gelu = 0.5x(1+tanh(u)) = x*(1-r), r=1/(1+e^{2u})
__device__ __forceinline__ float fast_gelu(float x) {
  const float u = x * fmaf(0.0356774081f, x * x, 0.7978845608f);
  const float e = __builtin_amdgcn_exp2f(u * 2.885390082f);   // e^{2u}
  const float r = __builtin_amdgcn_rcpf(e + 1.0f);
  return fmaf(-x, r, x);
}

// ---------------- bf16 MFMA GEMM: C = A[M,Kd] @ Bt[N,Kd]^T + bias (+res) (+gelu)
// A and Bt chunk-swizzled. flags: 1=fast-gelu, 2=bf16 out, 4=swizzled bf16 out, 8=res is bf16.
// 1-D grid, XCD-aware remap (requires gy % 8 == 0).
template<int BM, int BN, int NI, int NJ>
__global__ __launch_bounds__(256) void gemm_bt_t(
    const short* __restrict__ A, const short* __restrict__ Bt,
    const float* __restrict__ bias, const void* __restrict__ res,
    void* __restrict__ Cout, int M, int N, int Kd, int flags, int gx) {
  __shared__ short lA[BM * 64];
  __shared__ short lB[BN * 64];
  const int gy   = gridDim.x / gx;
  const int xcd  = blockIdx.x & 7;
  const int seq  = blockIdx.x >> 3;
  const int rpx  = gy >> 3;                 // row-tiles per XCD
  const int by   = xcd * rpx + seq / gx;
  const int bx   = seq % gx;
  const int tid  = threadIdx.x;
  const int wave = tid >> 6, lane = tid & 63;
  const int block_m = by * BM, block_n = bx * BN;
  const int wm = (wave & 1) * (BM / 2), wn = (wave >> 1) * (BN / 2);
  const int l15 = lane & 15, quad = lane >> 4, l7 = lane & 7;
  f32x4 acc[NI][NJ] = {};

  for (int k0 = 0; k0 < Kd; k0 += 64) {
    __syncthreads();               // previous tile's LDS reads complete
#pragma unroll
    for (int i = 0; i < BM / 32; ++i) {
      const int cb = wave * (BM * 2) + i * 64;
      const int c  = cb + lane;                 // chunk of 8 bf16
      async_copy16(A + (size_t)(block_m + (c >> 3)) * Kd + k0 + (c & 7) * 8,
                   &lA[cb * 8]);
    }
#pragma unroll
    for (int i = 0; i < BN / 32; ++i) {
      const int cb = wave * (BN * 2) + i * 64;
      const int c  = cb + lane;
      async_copy16(Bt + (size_t)(block_n + (c >> 3)) * Kd + k0 + (c & 7) * 8,
                   &lB[cb * 8]);
    }
    __syncthreads();               // barrier drains vmcnt => LDS tiles ready
#pragma unroll
    for (int ks = 0; ks < 2; ++ks) {
      bf8 af[NI], bfr[NJ];
#pragma unroll
      for (int i = 0; i < NI; ++i)
        af[i] = *(const bf8*)&lA[(wm + i * 16 + l15) * 64 + (((ks * 4 + quad) ^ l7) << 3)];
#pragma unroll
      for (int j = 0; j < NJ; ++j)
        bfr[j] = *(const bf8*)&lB[(wn + j * 16 + l15) * 64 + (((ks * 4 + quad) ^ l7) << 3)];
#pragma unroll
      for (int i = 0; i < NI; ++i)
#pragma unroll
        for (int j = 0; j < NJ; ++j)
          acc[i][j] = __builtin_amdgcn_mfma_f32_16x16x32_bf16(af[i], bfr[j], acc[i][j], 0, 0, 0);
    }
  }

  const int do_gelu = flags & 1, out_bf = flags & 2, out_sw = flags & 4, res_bf = flags & 8;
#pragma unroll
  for (int i = 0; i < NI; ++i) {
    const int mbase = block_m + wm + i * 16 + (lane >> 4) * 4;
#pragma unroll
    for (int j = 0; j < NJ; ++j) {
      const int col = block_n + wn + j * 16 + l15;
      const float bb = bias[col];
#pragma unroll
      for (int r = 0; r < 4; ++r) {
        const int row = mbase + r;
        const size_t idx = (size_t)row * N + col;
        float v = acc[i][j][r] + bb;
        if (res) v += res_bf ? bf2f(((const short*)res)[idx]) : ((const float*)res)[idx];
        if (do_gelu) v = fast_gelu(v);
        if (out_bf) {
          const int oc = out_sw ? swz64(row, col) : col;
          ((short*)Cout)[(size_t)row * N + oc] = f2bf(v);
        } else {
          ((float*)Cout)[idx] = v;
        }
      }
    }
  }
}

// ---------------- transpose + convert: W[K,N] fp32 -> Wt[N,K] bf16 (chunk-swizzled)
__global__ __launch_bounds__(256) void tconv_k(const float* __restrict__ W,
                                               short* __restrict__ Wt, int K, int N) {
  __shared__ float s[32][33];
  const int tx = threadIdx.x & 31, ty = threadIdx.x >> 5;  // ty 0..7
  const int k0 = blockIdx.y * 32, n0 = blockIdx.x * 32;
#pragma unroll
  for (int r = 0; r < 4; ++r)
    s[ty * 4 + r][tx] = W[(size_t)(k0 + ty * 4 + r) * N + n0 + tx];
  __syncthreads();
#pragma unroll
  for (int r = 0; r < 4; ++r) {
    const int n = n0 + ty * 4 + r;
    Wt[(size_t)n * K + swz64(n, k0 + tx)] = f2bf(s[tx][ty * 4 + r]);
  }
}

// ---------------- fp32 -> bf16 elementwise (chunk-swizzled, width 512)
__global__ void cvt_k(const float* __restrict__ x, short* __restrict__ y, int n) {
  const int i = blockIdx.x * blockDim.x + threadIdx.x;
  if (i < n) {
    const int row = i >> 9, col = i & 511;
    y[((size_t)row << 9) | swz64(row, col)] = f2bf(x[i]);
  }
}

// ---------------- concat two bias vectors [n]+[n] -> [2n]
__global__ void concat2_k(const float* __restrict__ a, const float* __restrict__ b,
                          float* __restrict__ o, int n) {
  const int i = blockIdx.x * blockDim.x + threadIdx.x;
  if (i < n) o[i] = a[i];
  else if (i < 2 * n) o[i] = b[i - n];
}

// ---------------- block reduction helper (256 threads)
__device__ __forceinline__ float block_sum(float s, float* red, int tid) {
  red[tid] = s; __syncthreads();
  for (int o = 128; o > 0; o >>= 1) {
    if (tid < o) red[tid] += red[tid + o];
    __syncthreads();
  }
  float r = red[0];
  __syncthreads();
  return r;
}

// ---------------- LayerNorm, bf16 in: out(bf16, swizzled) = LN(in) * g + b
__global__ __launch_bounds__(256) void ln_bf_k(const short* __restrict__ in,
                                               const float* __restrict__ g,
                                               const float* __restrict__ b,
                                               short* __restrict__ out) {
  __shared__ float red[256];
  const int row = blockIdx.x, tid = threadIdx.x;
  const short2 xv = *(const short2*)&in[(size_t)row * D_ + 2 * tid];
  const float v0 = bf2f(xv.x), v1 = bf2f(xv.y);
  const float mean = block_sum(v0 + v1, red, tid) * (1.0f / D_);
  const float d0 = v0 - mean, d1 = v1 - mean;
  const float var = block_sum(d0 * d0 + d1 * d1, red, tid) * (1.0f / D_);
  const float inv = rsqrtf(var + EPS_);
  const float2 gg = *(const float2*)&g[2 * tid];
  const float2 bb = *(const float2*)&b[2 * tid];
  short2 o;
  o.x = f2bf(d0 * inv * gg.x + bb.x);
  o.y = f2bf(d1 * inv * gg.y + bb.y);
  *(short2*)&out[(size_t)row * D_ + swz64(row, 2 * tid)] = o;
}

// ---------------- gate + LN, both streams (X bf16 in): Xk(bf16) ; LN out swizzled bf16
__global__ __launch_bounds__(256) void scale_ln_k(
    const short* __restrict__ X, const float* __restrict__ Ain,
    const float* __restrict__ g, const float* __restrict__ b,
    short* __restrict__ Xk, short* __restrict__ out) {
  __shared__ float red[256];
  const int row = blockIdx.x, tid = threadIdx.x;
  const int kk = row / M_, rm = row % M_;
  const float a = Ain[(size_t)rm * K_ + kk];
  const float w = __builtin_amdgcn_rcpf(1.0f + __expf(-ALPHA_ * (a - BETA_)));
  const short2 xv = *(const short2*)&X[(size_t)rm * D_ + 2 * tid];
  const float v0 = bf2f(xv.x) * w, v1 = bf2f(xv.y) * w;
  short2 xo; xo.x = f2bf(v0); xo.y = f2bf(v1);
  *(short2*)&Xk[(size_t)row * D_ + 2 * tid] = xo;
  const float mean = block_sum(v0 + v1, red, tid) * (1.0f / D_);
  const float d0 = v0 - mean, d1 = v1 - mean;
  const float var = block_sum(d0 * d0 + d1 * d1, red, tid) * (1.0f / D_);
  const float inv = rsqrtf(var + EPS_);
  const float2 gg = *(const float2*)&g[2 * tid];
  const float2 bb = *(const float2*)&b[2 * tid];
  short2 o;
  o.x = f2bf(d0 * inv * gg.x + bb.x);
  o.y = f2bf(d1 * inv * gg.y + bb.y);
  *(short2*)&out[(size_t)row * D_ + swz64(row, 2 * tid)] = o;
}

// ---------------- final LN: in = T2 (y+h2, fp32) + tag; scatter to concat layout
__global__ __launch_bounds__(256) void final_ln_k(
    const float* __restrict__ t2, const float* __restrict__ tags,
    const float* __restrict__ g, const float* __restrict__ b,
    float* __restrict__ out) {
  __shared__ float red[256];
  const int row = blockIdx.x, tid = threadIdx.x;
  const int kk = row / M_, rm = row % M_;
  const int bb = rm / T_, t = rm % T_;
  const size_t orow = (size_t)bb * (K_ * T_) + (size_t)kk * T_ + t;
  const float v0 = t2[(size_t)row * D_ + tid]       + tags[(size_t)kk * D_ + tid];
  const float v1 = t2[(size_t)row * D_ + tid + 256] + tags[(size_t)kk * D_ + tid + 256];
  const float mean = block_sum(v0 + v1, red, tid) * (1.0f / D_);
  const float d0 = v0 - mean, d1 = v1 - mean;
  const float var = block_sum(d0 * d0 + d1 * d1, red, tid) * (1.0f / D_);
  const float inv = rsqrtf(var + EPS_);
  out[orow * D_ + tid]       = d0 * inv * g[tid]       + b[tid];
  out[orow * D_ + tid + 256] = d1 * inv * g[tid + 256] + b[tid + 256];
}

// ---------------- MFMA banded attention, both streams
// q [2M,D] bf16 (unswizzled); KVp [M,2D] bf16 (unswizzled); out bf16 swizzled
#define QT_  64
#define KT_  (QT_ + 2 * BAND_)   // 112 rows
#define SKQ_ 72                  // row stride (shorts) for sK/sQ/sP
#define STV_ 136                 // row stride (shorts) for sVt
__global__ __launch_bounds__(256) void attn_mfma_k(
    const short* __restrict__ q, const short* __restrict__ KVp,
    short* __restrict__ out) {
  __shared__ short sK[KT_ * SKQ_];
  __shared__ short sQ[QT_ * SKQ_];
  __shared__ short sVt[DH_ * STV_];     // transposed: [dim][key row]
  __shared__ short sP[4][16 * SKQ_];
  const int t0 = blockIdx.x * QT_;
  const int h  = blockIdx.y;
  const int z  = blockIdx.z;            // kk*B + b
  const int b  = z % B_;
  const int tid = threadIdx.x;
  const int wave = tid >> 6, lane = tid & 63;
  const int rr = tid >> 5, c2 = tid & 31;

  for (int r0 = 0; r0 < KT_; r0 += 8) {
    const int r = r0 + rr;
    const int s = t0 - BAND_ + r;
    short2 kv = {0, 0}, vv = {0, 0};
    if (s >= 0 && s < T_) {
      const size_t g = (size_t)(b * T_ + s) * (2 * D_) + h * DH_ + c2 * 2;
      kv = *(const short2*)&KVp[g];
      vv = *(const short2*)&KVp[g + D_];
    }
    *(short2*)&sK[r * SKQ_ + c2 * 2] = kv;
    sVt[(c2 * 2)     * STV_ + r] = vv.x;
    sVt[(c2 * 2 + 1) * STV_ + r] = vv.y;
  }
  for (int r0 = 0; r0 < QT_; r0 += 8) {
    const int r = r0 + rr;
    const size_t g = (size_t)(z * T_ + t0 + r) * D_ + h * DH_ + c2 * 2;
    *(short2*)&sQ[r * SKQ_ + c2 * 2] = *(const short2*)&q[g];
  }
  __syncthreads();

  const int qg  = wave * 16;            // query group base (also key window base)
  const int l15 = lane & 15, quad = lane >> 4;

  // ---- S = Q16x64 @ K64x64^T  (8 MFMAs)
  bf8 qa0 = *(const bf8*)&sQ[(qg + l15) * SKQ_ + quad * 8];
  bf8 qa1 = *(const bf8*)&sQ[(qg + l15) * SKQ_ + 32 + quad * 8];
  f32x4 acc[4];
#pragma unroll
  for (int j = 0; j < 4; ++j) {
    const bf8 kb0 = *(const bf8*)&sK[(qg + j * 16 + l15) * SKQ_ + quad * 8];
    const bf8 kb1 = *(const bf8*)&sK[(qg + j * 16 + l15) * SKQ_ + 32 + quad * 8];
    f32x4 z4 = {0.f, 0.f, 0.f, 0.f};
    acc[j] = __builtin_amdgcn_mfma_f32_16x16x32_bf16(qa0, kb0, z4, 0, 0, 0);
    acc[j] = __builtin_amdgcn_mfma_f32_16x16x32_bf16(qa1, kb1, acc[j], 0, 0, 0);
  }

  // ---- banded softmax on C-layout rows (row = quad*4+reg, col = j*16+l15)
#pragma unroll
  for (int reg = 0; reg < 4; ++reg) {
    const int i = quad * 4 + reg;       // query within group
    float sc[4];
    float mx = -1e30f;
#pragma unroll
    for (int j = 0; j < 4; ++j) {
      const int c = j * 16 + l15;       // key within 64-window
      const int s = t0 + qg - BAND_ + c;
      const int rel = c - i;            // in [0,48] when inside band
      const bool valid = (rel >= 0) && (rel <= 2 * BAND_) && (s >= 0) && (s < T_);
      sc[j] = valid ? acc[j][reg] * 0.125f : -1e30f;
      mx = fmaxf(mx, sc[j]);
    }
    for (int o = 1; o < 16; o <<= 1) mx = fmaxf(mx, __shfl_xor(mx, o));
    float p[4], se = 0.0f;
#pragma unroll
    for (int j = 0; j < 4; ++j) {
      p[j] = (sc[j] > -1e29f) ? __expf(sc[j] - mx) : 0.0f;
      se += p[j];
    }
    for (int o = 1; o < 16; o <<= 1) se += __shfl_xor(se, o);
    const float inv = __builtin_amdgcn_rcpf(se);
#pragma unroll
    for (int j = 0; j < 4; ++j)
      sP[wave][i * SKQ_ + j * 16 + l15] = f2bf(p[j] * inv);
  }

  // ---- O = P16x64 @ V64x64  (8 MFMAs; V from transposed LDS)
  const bf8 pa0 = *(const bf8*)&sP[wave][l15 * SKQ_ + quad * 8];
  const bf8 pa1 = *(const bf8*)&sP[wave][l15 * SKQ_ + 32 + quad * 8];
  f32x4 oacc[4] = {};
#pragma unroll
  for (int dt = 0; dt < 4; ++dt) {
    const bf8 vb0 = *(const bf8*)&sVt[(dt * 16 + l15) * STV_ + qg + quad * 8];
    const bf8 vb1 = *(const bf8*)&sVt[(dt * 16 + l15) * STV_ + qg + 32 + quad * 8];
    oacc[dt] = __builtin_amdgcn_mfma_f32_16x16x32_bf16(pa0, vb0, oacc[dt], 0, 0, 0);
    oacc[dt] = __builtin_amdgcn_mfma_f32_16x16x32_bf16(pa1, vb1, oacc[dt], 0, 0, 0);
  }
#pragma unroll
  for (int dt = 0; dt < 4; ++dt)
#pragma unroll
    for (int reg = 0; reg < 4; ++reg) {
      const int i = quad * 4 + reg;
      const int row = t0 + qg + i;
      const int col = h * DH_ + dt * 16 + l15;
      out[(size_t)(z * T_ + row) * D_ + swz64(row, col)] = f2bf(oacc[dt][reg]);
    }
}

extern "C" void kernel_launch(void* const* d_in, const int* in_sizes, int n_in,
                              void* d_out, int out_size, void* d_ws, size_t ws_size,
                              hipStream_t stream) {
  const float* x_m    = (const float*)d_in[0];
  const float* A      = (const float*)d_in[1];
  const float* W_in   = (const float*)d_in[2];
  const float* b_in   = (const float*)d_in[3];
  const float* ln_q_g = (const float*)d_in[4];
  const float* ln_q_b = (const float*)d_in[5];
  const float* ln_kv_g= (const float*)d_in[6];
  const float* ln_kv_b= (const float*)d_in[7];
  const float* Wq     = (const float*)d_in[8];
  const float* bq     = (const float*)d_in[9];
  const float* Wk     = (const float*)d_in[10];
  const float* bk     = (const float*)d_in[11];
  const float* Wv     = (const float*)d_in[12];
  const float* bv     = (const float*)d_in[13];
  const float* Wo     = (const float*)d_in[14];
  const float* bo     = (const float*)d_in[15];
  const float* ln_f_g = (const float*)d_in[16];
  const float* ln_f_b = (const float*)d_in[17];
  const float* W1     = (const float*)d_in[18];
  const float* b1     = (const float*)d_in[19];
  const float* W2     = (const float*)d_in[20];
  const float* b2     = (const float*)d_in[21];
  const float* ln_s_g = (const float*)d_in[22];
  const float* ln_s_b = (const float*)d_in[23];
  const float* tags   = (const float*)d_in[24];
  float* out = (float*)d_out;

  const size_t MD = (size_t)M_ * D_;
  // fp32 buffers
  float* T2  = (float*)d_ws;           // [2M,D]  y + h2
  float* bkv = T2 + 2 * MD;            // [1024]
  // bf16 buffers
  short* X    = (short*)(bkv + 1024);  // [M,D]  unswizzled
  short* Xk2  = X    + MD;             // [2M,D] gated X, then y (bf16, unswizzled)
  short* LNb2 = Xk2  + 2 * MD;         // [2M,D]; first MD also = KV LN (swizzled)
  short* qb2  = LNb2 + 2 * MD;         // [2M,D]; first MD also = xb (x_m bf16 swz)
  short* KVpb = qb2  + 2 * MD;         // [M,2D] interleaved K|V (unswizzled)
  short* H1b  = KVpb + 2 * MD;         // [2M,4D] swizzled
  short* WtIn = H1b + (size_t)M2_ * 4 * D_;
  short* WtQ  = WtIn + (size_t)D_ * DIN_;
  short* WtKV = WtQ  + (size_t)D_ * D_;        // [2D, D]
  short* WtO  = WtKV + (size_t)2 * D_ * D_;
  short* Wt1  = WtO  + (size_t)D_ * D_;        // [4D, D]
  short* Wt2  = Wt1  + (size_t)4 * D_ * D_;    // [D, 4D]
  short* xb   = qb2;                   // alias (used before Q GEMM)
  short* KVb  = LNb2;                  // alias (used before scale_ln)

  // ---- prep: weights to bf16 [N,K] swizzled, x_m to bf16 swizzled, concat K/V bias
  cvt_k<<<(M_ * DIN_ + 255) / 256, 256, 0, stream>>>(x_m, xb, M_ * DIN_);
  concat2_k<<<4, 256, 0, stream>>>(bk, bv, bkv, D_);
  tconv_k<<<dim3(D_/32,    DIN_/32),  256, 0, stream>>>(W_in, WtIn, DIN_, D_);
  tconv_k<<<dim3(D_/32,    D_/32),    256, 0, stream>>>(Wq,   WtQ,  D_,   D_);
  tconv_k<<<dim3(D_/32,    D_/32),    256, 0, stream>>>(Wk,   WtKV, D_,   D_);
  tconv_k<<<dim3(D_/32,    D_/32),    256, 0, stream>>>(Wv,   WtKV + (size_t)D_*D_, D_, D_);
  tconv_k<<<dim3(D_/32,    D_/32),    256, 0, stream>>>(Wo,   WtO,  D_,   D_);
  tconv_k<<<dim3((4*D_)/32, D_/32),   256, 0, stream>>>(W1,   Wt1,  D_,   4*D_);
  tconv_k<<<dim3(D_/32,  (4*D_)/32),  256, 0, stream>>>(W2,   Wt2,  4*D_, D_);

  // X = x_m @ W_in + b_in  (bf16 unswizzled out)
  gemm_bt_t<128,64,4,2><<<(D_/64) * (M_/128), 256, 0, stream>>>(
      xb, WtIn, b_in, nullptr, X, M_, D_, DIN_, 2, D_/64);
  // KVb = LN(X)  (swizzled bf16)
  ln_bf_k<<<M_, 256, 0, stream>>>(X, ln_kv_g, ln_kv_b, KVb);
  // K|V projection, N=1024 (bf16 out, UNswizzled: consumed by attention)
  gemm_bt_t<128,128,4,4><<<((2*D_)/128) * (M_/128), 256, 0, stream>>>(
      KVb, WtKV, bkv, nullptr, KVpb, M_, 2*D_, D_, 2, (2*D_)/128);

  // ---- both streams batched over 2M rows
  scale_ln_k<<<M2_, 256, 0, stream>>>(X, A, ln_q_g, ln_q_b, Xk2, LNb2);
  gemm_bt_t<128,128,4,4><<<(D_/128) * (M2_/128), 256, 0, stream>>>(
      LNb2, WtQ, bq, nullptr, qb2, M2_, D_, D_, 2, D_/128);  // q: unswizzled
  attn_mfma_k<<<dim3(T_/QT_, H_, B_*K_), 256, 0, stream>>>(qb2, KVpb, LNb2);
  // y = attn @ Wo + bo + Xk  (bf16 in-place, res bf16)
  gemm_bt_t<128,128,4,4><<<(D_/128) * (M2_/128), 256, 0, stream>>>(
      LNb2, WtO, bo, Xk2, Xk2, M2_, D_, D_, 2 | 8, D_/128);
  ln_bf_k<<<M2_, 256, 0, stream>>>(Xk2, ln_f_g, ln_f_b, LNb2);
  gemm_bt_t<128,128,4,4><<<((4*D_)/128) * (M2_/128), 256, 0, stream>>>(
      LNb2, Wt1, b1, nullptr, H1b, M2_, 4*D_, D_, 1 | 2 | 4, (4*D_)/128);
  // T2 = h1 @ W2 + b2 + y  (fp32 out, res bf16)
  gemm_bt_t<128,64,4,2><<<(D_/64) * (M2_/128), 256, 0, stream>>>(
      H1b, Wt2, b2, Xk2, T2, M2_, D_, 4*D_, 8, D_/64);
  final_ln_k<<<M2_, 256, 0, stream>>>(T2, tags, ln_s_g, ln_s_b, out);
}

// Round 10
// 343.404 us; speedup vs baseline: 1.1404x; 1.1188x over previous
//
#include <hip/hip_runtime.h>
#include <hip/hip_bf16.h>
#include <math.h>

#define B_    4
#define T_    1536
#define DIN_  512
#define D_    512
#define K_    2
#define H_    8
#define BAND_ 24
#define DH_   64
#define M_    (B_*T_)      // 6144 rows
#define M2_   (2*M_)       // both streams batched
#define ALPHA_ 6.0f
#define BETA_  0.5f
#define EPS_   1e-5f

using bf8  = __attribute__((ext_vector_type(8))) short;   // 8 bf16 (4 VGPRs)
using f32x4 = __attribute__((ext_vector_type(4))) float;  // 4 fp32 acc

__device__ __forceinline__ void async_copy16(const void* g, void* l) {
  __builtin_amdgcn_global_load_lds(
      (const __attribute__((address_space(1))) unsigned int*)g,
      (__attribute__((address_space(3))) unsigned int*)l, 16, 0, 0);
}

__device__ __forceinline__ short f2bf(float v) {
  __hip_bfloat16 h = (__hip_bfloat16)v;
  return *(short*)&h;
}
__device__ __forceinline__ float bf2f(short s) {
  union { unsigned u; float f; } c;
  c.u = ((unsigned)(unsigned short)s) << 16;
  return c.f;
}
// XOR-swizzle of 16B chunks within each 64-element column block (bank-conflict fix)
__device__ __forceinline__ int swz64(int row, int col) {
  return (col & ~63) | ((((col >> 3) ^ row) & 7) << 3) | (col & 7);
}
// tanh-form gelu, 7 VALU (2*log2e folded into polynomial), max err ~1e-3
__device__ __forceinline__ float fast_gelu(float x) {
  const float t = fmaf(0.1029504013f, x * x, 2.3021170686f);  // (a x^2 + b)*2*log2e
  const float e = __builtin_amdgcn_exp2f(x * t);              // e^{2u}
  const float r = __builtin_amdgcn_rcpf(e + 1.0f);
  return fmaf(-x, r, x);
}

// ---------------- bf16 MFMA GEMM: C = A[M,Kd] @ Bt[N,Kd]^T + bias (+res) (+gelu)
// A and Bt chunk-swizzled. FLAGS (compile-time): 1=gelu, 2=bf16 out, 4=swizzled out,
// 8=bf16 residual, 16=fp32 residual. 1-D grid, XCD-aware remap (gy % 8 == 0).
template<int BM, int BN, int NI, int NJ, int FLAGS>
__global__ __launch_bounds__(256) void gemm_bt_t(
    const short* __restrict__ A, const short* __restrict__ Bt,
    const float* __restrict__ bias, const void* __restrict__ res,
    void* __restrict__ Cout, int M, int N, int Kd, int gx) {
  __shared__ short lA[BM * 64];
  __shared__ short lB[BN * 64];
  const int gy   = gridDim.x / gx;
  const int xcd  = blockIdx.x & 7;
  const int seq  = blockIdx.x >> 3;
  const int rpx  = gy >> 3;                 // row-tiles per XCD
  const int by   = xcd * rpx + seq / gx;
  const int bx   = seq % gx;
  const int tid  = threadIdx.x;
  const int wave = tid >> 6, lane = tid & 63;
  const int block_m = by * BM, block_n = bx * BN;
  const int wm = (wave & 1) * (BM / 2), wn = (wave >> 1) * (BN / 2);
  const int l15 = lane & 15, quad = lane >> 4, l7 = lane & 7;
  f32x4 acc[NI][NJ] = {};

  for (int k0 = 0; k0 < Kd; k0 += 64) {
    __syncthreads();               // previous tile's LDS reads complete
#pragma unroll
    for (int i = 0; i < BM / 32; ++i) {
      const int cb = wave * (BM * 2) + i * 64;
      const int c  = cb + lane;                 // chunk of 8 bf16
      async_copy16(A + (size_t)(block_m + (c >> 3)) * Kd + k0 + (c & 7) * 8,
                   &lA[cb * 8]);
    }
#pragma unroll
    for (int i = 0; i < BN / 32; ++i) {
      const int cb = wave * (BN * 2) + i * 64;
      const int c  = cb + lane;
      async_copy16(Bt + (size_t)(block_n + (c >> 3)) * Kd + k0 + (c & 7) * 8,
                   &lB[cb * 8]);
    }
    __syncthreads();               // barrier drains vmcnt => LDS tiles ready
#pragma unroll
    for (int ks = 0; ks < 2; ++ks) {
      bf8 af[NI], bfr[NJ];
#pragma unroll
      for (int i = 0; i < NI; ++i)
        af[i] = *(const bf8*)&lA[(wm + i * 16 + l15) * 64 + (((ks * 4 + quad) ^ l7) << 3)];
#pragma unroll
      for (int j = 0; j < NJ; ++j)
        bfr[j] = *(const bf8*)&lB[(wn + j * 16 + l15) * 64 + (((ks * 4 + quad) ^ l7) << 3)];
#pragma unroll
      for (int i = 0; i < NI; ++i)
#pragma unroll
        for (int j = 0; j < NJ; ++j)
          acc[i][j] = __builtin_amdgcn_mfma_f32_16x16x32_bf16(af[i], bfr[j], acc[i][j], 0, 0, 0);
    }
  }

#pragma unroll
  for (int i = 0; i < NI; ++i) {
    const int mbase = block_m + wm + i * 16 + (lane >> 4) * 4;
#pragma unroll
    for (int j = 0; j < NJ; ++j) {
      const int col = block_n + wn + j * 16 + l15;
      const float bb = bias[col];
#pragma unroll
      for (int r = 0; r < 4; ++r) {
        const int row = mbase + r;
        const size_t idx = (size_t)row * N + col;
        float v = acc[i][j][r] + bb;
        if constexpr (FLAGS & 8)  v += bf2f(((const short*)res)[idx]);
        if constexpr (FLAGS & 16) v += ((const float*)res)[idx];
        if constexpr (FLAGS & 1)  v = fast_gelu(v);
        if constexpr (FLAGS & 2) {
          const int oc = (FLAGS & 4) ? swz64(row, col) : col;
          ((short*)Cout)[(size_t)row * N + oc] = f2bf(v);
        } else {
          ((float*)Cout)[idx] = v;
        }
      }
    }
  }
}

// ---------------- transpose + convert: W[K,N] fp32 -> Wt[N,K] bf16 (chunk-swizzled)
__global__ __launch_bounds__(256) void tconv_k(const float* __restrict__ W,
                                               short* __restrict__ Wt, int K, int N) {
  __shared__ float s[32][33];
  const int tx = threadIdx.x & 31, ty = threadIdx.x >> 5;  // ty 0..7
  const int k0 = blockIdx.y * 32, n0 = blockIdx.x * 32;
#pragma unroll
  for (int r = 0; r < 4; ++r)
    s[ty * 4 + r][tx] = W[(size_t)(k0 + ty * 4 + r) * N + n0 + tx];
  __syncthreads();
#pragma unroll
  for (int r = 0; r < 4; ++r) {
    const int n = n0 + ty * 4 + r;
    Wt[(size_t)n * K + swz64(n, k0 + tx)] = f2bf(s[tx][ty * 4 + r]);
  }
}

// ---------------- fp32 -> bf16 elementwise (chunk-swizzled, width 512)
__global__ void cvt_k(const float* __restrict__ x, short* __restrict__ y, int n) {
  const int i = blockIdx.x * blockDim.x + threadIdx.x;
  if (i < n) {
    const int row = i >> 9, col = i & 511;
    y[((size_t)row << 9) | swz64(row, col)] = f2bf(x[i]);
  }
}

// ---------------- concat two bias vectors [n]+[n] -> [2n]
__global__ void concat2_k(const float* __restrict__ a, const float* __restrict__ b,
                          float* __restrict__ o, int n) {
  const int i = blockIdx.x * blockDim.x + threadIdx.x;
  if (i < n) o[i] = a[i];
  else if (i < 2 * n) o[i] = b[i - n];
}

// ---------------- block reduction helper (256 threads)
__device__ __forceinline__ float block_sum(float s, float* red, int tid) {
  red[tid] = s; __syncthreads();
  for (int o = 128; o > 0; o >>= 1) {
    if (tid < o) red[tid] += red[tid + o];
    __syncthreads();
  }
  float r = red[0];
  __syncthreads();
  return r;
}

// ---------------- LayerNorm, bf16 in: out(bf16, swizzled) = LN(in) * g + b
__global__ __launch_bounds__(256) void ln_bf_k(const short* __restrict__ in,
                                               const float* __restrict__ g,
                                               const float* __restrict__ b,
                                               short* __restrict__ out) {
  __shared__ float red[256];
  const int row = blockIdx.x, tid = threadIdx.x;
  const short2 xv = *(const short2*)&in[(size_t)row * D_ + 2 * tid];
  const float v0 = bf2f(xv.x), v1 = bf2f(xv.y);
  const float mean = block_sum(v0 + v1, red, tid) * (1.0f / D_);
  const float d0 = v0 - mean, d1 = v1 - mean;
  const float var = block_sum(d0 * d0 + d1 * d1, red, tid) * (1.0f / D_);
  const float inv = rsqrtf(var + EPS_);
  const float2 gg = *(const float2*)&g[2 * tid];
  const float2 bb = *(const float2*)&b[2 * tid];
  short2 o;
  o.x = f2bf(d0 * inv * gg.x + bb.x);
  o.y = f2bf(d1 * inv * gg.y + bb.y);
  *(short2*)&out[(size_t)row * D_ + swz64(row, 2 * tid)] = o;
}

// ---------------- gate + LN, both streams (X bf16 in): Xk(bf16) ; LN out swizzled bf16
__global__ __launch_bounds__(256) void scale_ln_k(
    const short* __restrict__ X, const float* __restrict__ Ain,
    const float* __restrict__ g, const float* __restrict__ b,
    short* __restrict__ Xk, short* __restrict__ out) {
  __shared__ float red[256];
  const int row = blockIdx.x, tid = threadIdx.x;
  const int kk = row / M_, rm = row % M_;
  const float a = Ain[(size_t)rm * K_ + kk];
  const float w = __builtin_amdgcn_rcpf(1.0f + __expf(-ALPHA_ * (a - BETA_)));
  const short2 xv = *(const short2*)&X[(size_t)rm * D_ + 2 * tid];
  const float v0 = bf2f(xv.x) * w, v1 = bf2f(xv.y) * w;
  short2 xo; xo.x = f2bf(v0); xo.y = f2bf(v1);
  *(short2*)&Xk[(size_t)row * D_ + 2 * tid] = xo;
  const float mean = block_sum(v0 + v1, red, tid) * (1.0f / D_);
  const float d0 = v0 - mean, d1 = v1 - mean;
  const float var = block_sum(d0 * d0 + d1 * d1, red, tid) * (1.0f / D_);
  const float inv = rsqrtf(var + EPS_);
  const float2 gg = *(const float2*)&g[2 * tid];
  const float2 bb = *(const float2*)&b[2 * tid];
  short2 o;
  o.x = f2bf(d0 * inv * gg.x + bb.x);
  o.y = f2bf(d1 * inv * gg.y + bb.y);
  *(short2*)&out[(size_t)row * D_ + swz64(row, 2 * tid)] = o;
}

// ---------------- final LN: in = T2 (y+h2, fp32) + tag; scatter to concat layout
__global__ __launch_bounds__(256) void final_ln_k(
    const float* __restrict__ t2, const float* __restrict__ tags,
    const float* __restrict__ g, const float* __restrict__ b,
    float* __restrict__ out) {
  __shared__ float red[256];
  const int row = blockIdx.x, tid = threadIdx.x;
  const int kk = row / M_, rm = row % M_;
  const int bb = rm / T_, t = rm % T_;
  const size_t orow = (size_t)bb * (K_ * T_) + (size_t)kk * T_ + t;
  const float v0 = t2[(size_t)row * D_ + tid]       + tags[(size_t)kk * D_ + tid];
  const float v1 = t2[(size_t)row * D_ + tid + 256] + tags[(size_t)kk * D_ + tid + 256];
  const float mean = block_sum(v0 + v1, red, tid) * (1.0f / D_);
  const float d0 = v0 - mean, d1 = v1 - mean;
  const float var = block_sum(d0 * d0 + d1 * d1, red, tid) * (1.0f / D_);
  const float inv = rsqrtf(var + EPS_);
  out[orow * D_ + tid]       = d0 * inv * g[tid]       + b[tid];
  out[orow * D_ + tid + 256] = d1 * inv * g[tid + 256] + b[tid + 256];
}

// ---------------- MFMA banded attention, both streams
// q [2M,D] bf16 (unswizzled); KVp [M,2D] bf16 (unswizzled); out bf16 swizzled
#define QT_  64
#define KT_  (QT_ + 2 * BAND_)   // 112 rows
#define SKQ_ 72                  // row stride (shorts) for sK/sQ/sP
#define STV_ 136                 // row stride (shorts) for sVt
__global__ __launch_bounds__(256) void attn_mfma_k(
    const short* __restrict__ q, const short* __restrict__ KVp,
    short* __restrict__ out) {
  __shared__ short sK[KT_ * SKQ_];
  __shared__ short sQ[QT_ * SKQ_];
  __shared__ short sVt[DH_ * STV_];     // transposed: [dim][key row]
  __shared__ short sP[4][16 * SKQ_];
  const int t0 = blockIdx.x * QT_;
  const int h  = blockIdx.y;
  const int z  = blockIdx.z;            // kk*B + b
  const int b  = z % B_;
  const int tid = threadIdx.x;
  const int wave = tid >> 6, lane = tid & 63;
  const int rr = tid >> 5, c2 = tid & 31;

  for (int r0 = 0; r0 < KT_; r0 += 8) {
    const int r = r0 + rr;
    const int s = t0 - BAND_ + r;
    short2 kv = {0, 0}, vv = {0, 0};
    if (s >= 0 && s < T_) {
      const size_t g = (size_t)(b * T_ + s) * (2 * D_) + h * DH_ + c2 * 2;
      kv = *(const short2*)&KVp[g];
      vv = *(const short2*)&KVp[g + D_];
    }
    *(short2*)&sK[r * SKQ_ + c2 * 2] = kv;
    sVt[(c2 * 2)     * STV_ + r] = vv.x;
    sVt[(c2 * 2 + 1) * STV_ + r] = vv.y;
  }
  for (int r0 = 0; r0 < QT_; r0 += 8) {
    const int r = r0 + rr;
    const size_t g = (size_t)(z * T_ + t0 + r) * D_ + h * DH_ + c2 * 2;
    *(short2*)&sQ[r * SKQ_ + c2 * 2] = *(const short2*)&q[g];
  }
  __syncthreads();

  const int qg  = wave * 16;            // query group base (also key window base)
  const int l15 = lane & 15, quad = lane >> 4;

  // ---- S = Q16x64 @ K64x64^T  (8 MFMAs)
  bf8 qa0 = *(const bf8*)&sQ[(qg + l15) * SKQ_ + quad * 8];
  bf8 qa1 = *(const bf8*)&sQ[(qg + l15) * SKQ_ + 32 + quad * 8];
  f32x4 acc[4];
#pragma unroll
  for (int j = 0; j < 4; ++j) {
    const bf8 kb0 = *(const bf8*)&sK[(qg + j * 16 + l15) * SKQ_ + quad * 8];
    const bf8 kb1 = *(const bf8*)&sK[(qg + j * 16 + l15) * SKQ_ + 32 + quad * 8];
    f32x4 z4 = {0.f, 0.f, 0.f, 0.f};
    acc[j] = __builtin_amdgcn_mfma_f32_16x16x32_bf16(qa0, kb0, z4, 0, 0, 0);
    acc[j] = __builtin_amdgcn_mfma_f32_16x16x32_bf16(qa1, kb1, acc[j], 0, 0, 0);
  }

  // ---- banded softmax on C-layout rows (row = quad*4+reg, col = j*16+l15)
#pragma unroll
  for (int reg = 0; reg < 4; ++reg) {
    const int i = quad * 4 + reg;       // query within group
    float sc[4];
    float mx = -1e30f;
#pragma unroll
    for (int j = 0; j < 4; ++j) {
      const int c = j * 16 + l15;       // key within 64-window
      const int s = t0 + qg - BAND_ + c;
      const int rel = c - i;            // in [0,48] when inside band
      const bool valid = (rel >= 0) && (rel <= 2 * BAND_) && (s >= 0) && (s < T_);
      sc[j] = valid ? acc[j][reg] * 0.125f : -1e30f;
      mx = fmaxf(mx, sc[j]);
    }
    for (int o = 1; o < 16; o <<= 1) mx = fmaxf(mx, __shfl_xor(mx, o));
    float p[4], se = 0.0f;
#pragma unroll
    for (int j = 0; j < 4; ++j) {
      p[j] = (sc[j] > -1e29f) ? __expf(sc[j] - mx) : 0.0f;
      se += p[j];
    }
    for (int o = 1; o < 16; o <<= 1) se += __shfl_xor(se, o);
    const float inv = __builtin_amdgcn_rcpf(se);
#pragma unroll
    for (int j = 0; j < 4; ++j)
      sP[wave][i * SKQ_ + j * 16 + l15] = f2bf(p[j] * inv);
  }

  // ---- O = P16x64 @ V64x64  (8 MFMAs; V from transposed LDS)
  const bf8 pa0 = *(const bf8*)&sP[wave][l15 * SKQ_ + quad * 8];
  const bf8 pa1 = *(const bf8*)&sP[wave][l15 * SKQ_ + 32 + quad * 8];
  f32x4 oacc[4] = {};
#pragma unroll
  for (int dt = 0; dt < 4; ++dt) {
    const bf8 vb0 = *(const bf8*)&sVt[(dt * 16 + l15) * STV_ + qg + quad * 8];
    const bf8 vb1 = *(const bf8*)&sVt[(dt * 16 + l15) * STV_ + qg + 32 + quad * 8];
    oacc[dt] = __builtin_amdgcn_mfma_f32_16x16x32_bf16(pa0, vb0, oacc[dt], 0, 0, 0);
    oacc[dt] = __builtin_amdgcn_mfma_f32_16x16x32_bf16(pa1, vb1, oacc[dt], 0, 0, 0);
  }
#pragma unroll
  for (int dt = 0; dt < 4; ++dt)
#pragma unroll
    for (int reg = 0; reg < 4; ++reg) {
      const int i = quad * 4 + reg;
      const int row = t0 + qg + i;
      const int col = h * DH_ + dt * 16 + l15;
      out[(size_t)(z * T_ + row) * D_ + swz64(row, col)] = f2bf(oacc[dt][reg]);
    }
}

extern "C" void kernel_launch(void* const* d_in, const int* in_sizes, int n_in,
                              void* d_out, int out_size, void* d_ws, size_t ws_size,
                              hipStream_t stream) {
  const float* x_m    = (const float*)d_in[0];
  const float* A      = (const float*)d_in[1];
  const float* W_in   = (const float*)d_in[2];
  const float* b_in   = (const float*)d_in[3];
  const float* ln_q_g = (const float*)d_in[4];
  const float* ln_q_b = (const float*)d_in[5];
  const float* ln_kv_g= (const float*)d_in[6];
  const float* ln_kv_b= (const float*)d_in[7];
  const float* Wq     = (const float*)d_in[8];
  const float* bq     = (const float*)d_in[9];
  const float* Wk     = (const float*)d_in[10];
  const float* bk     = (const float*)d_in[11];
  const float* Wv     = (const float*)d_in[12];
  const float* bv     = (const float*)d_in[13];
  const float* Wo     = (const float*)d_in[14];
  const float* bo     = (const float*)d_in[15];
  const float* ln_f_g = (const float*)d_in[16];
  const float* ln_f_b = (const float*)d_in[17];
  const float* W1     = (const float*)d_in[18];
  const float* b1     = (const float*)d_in[19];
  const float* W2     = (const float*)d_in[20];
  const float* b2     = (const float*)d_in[21];
  const float* ln_s_g = (const float*)d_in[22];
  const float* ln_s_b = (const float*)d_in[23];
  const float* tags   = (const float*)d_in[24];
  float* out = (float*)d_out;

  const size_t MD = (size_t)M_ * D_;
  // fp32 buffers
  float* T2  = (float*)d_ws;           // [2M,D]  y + h2
  float* bkv = T2 + 2 * MD;            // [1024]
  // bf16 buffers
  short* X    = (short*)(bkv + 1024);  // [M,D]  unswizzled
  short* Xk2  = X    + MD;             // [2M,D] gated X, then y (bf16, unswizzled)
  short* LNb2 = Xk2  + 2 * MD;         // [2M,D]; first MD also = KV LN (swizzled)
  short* qb2  = LNb2 + 2 * MD;         // [2M,D]; first MD also = xb (x_m bf16 swz)
  short* KVpb = qb2  + 2 * MD;         // [M,2D] interleaved K|V (unswizzled)
  short* H1b  = KVpb + 2 * MD;         // [2M,4D] swizzled
  short* WtIn = H1b + (size_t)M2_ * 4 * D_;
  short* WtQ  = WtIn + (size_t)D_ * DIN_;
  short* WtKV = WtQ  + (size_t)D_ * D_;        // [2D, D]
  short* WtO  = WtKV + (size_t)2 * D_ * D_;
  short* Wt1  = WtO  + (size_t)D_ * D_;        // [4D, D]
  short* Wt2  = Wt1  + (size_t)4 * D_ * D_;    // [D, 4D]
  short* xb   = qb2;                   // alias (used before Q GEMM)
  short* KVb  = LNb2;                  // alias (used before scale_ln)

  // ---- prep: weights to bf16 [N,K] swizzled, x_m to bf16 swizzled, concat K/V bias
  cvt_k<<<(M_ * DIN_ + 255) / 256, 256, 0, stream>>>(x_m, xb, M_ * DIN_);
  concat2_k<<<4, 256, 0, stream>>>(bk, bv, bkv, D_);
  tconv_k<<<dim3(D_/32,    DIN_/32),  256, 0, stream>>>(W_in, WtIn, DIN_, D_);
  tconv_k<<<dim3(D_/32,    D_/32),    256, 0, stream>>>(Wq,   WtQ,  D_,   D_);
  tconv_k<<<dim3(D_/32,    D_/32),    256, 0, stream>>>(Wk,   WtKV, D_,   D_);
  tconv_k<<<dim3(D_/32,    D_/32),    256, 0, stream>>>(Wv,   WtKV + (size_t)D_*D_, D_, D_);
  tconv_k<<<dim3(D_/32,    D_/32),    256, 0, stream>>>(Wo,   WtO,  D_,   D_);
  tconv_k<<<dim3((4*D_)/32, D_/32),   256, 0, stream>>>(W1,   Wt1,  D_,   4*D_);
  tconv_k<<<dim3(D_/32,  (4*D_)/32),  256, 0, stream>>>(W2,   Wt2,  4*D_, D_);

  // X = x_m @ W_in + b_in  (bf16 unswizzled out)
  gemm_bt_t<128,64,4,2, 2><<<(D_/64) * (M_/128), 256, 0, stream>>>(
      xb, WtIn, b_in, nullptr, X, M_, D_, DIN_, D_/64);
  // KVb = LN(X)  (swizzled bf16)
  ln_bf_k<<<M_, 256, 0, stream>>>(X, ln_kv_g, ln_kv_b, KVb);
  // K|V projection, N=1024 (bf16 out, UNswizzled: consumed by attention)
  gemm_bt_t<128,128,4,4, 2><<<((2*D_)/128) * (M_/128), 256, 0, stream>>>(
      KVb, WtKV, bkv, nullptr, KVpb, M_, 2*D_, D_, (2*D_)/128);

  // ---- both streams batched over 2M rows
  scale_ln_k<<<M2_, 256, 0, stream>>>(X, A, ln_q_g, ln_q_b, Xk2, LNb2);
  gemm_bt_t<128,128,4,4, 2><<<(D_/128) * (M2_/128), 256, 0, stream>>>(
      LNb2, WtQ, bq, nullptr, qb2, M2_, D_, D_, D_/128);     // q: unswizzled
  attn_mfma_k<<<dim3(T_/QT_, H_, B_*K_), 256, 0, stream>>>(qb2, KVpb, LNb2);
  // y = attn @ Wo + bo + Xk  (bf16 in-place, bf16 res)
  gemm_bt_t<128,128,4,4, 2|8><<<(D_/128) * (M2_/128), 256, 0, stream>>>(
      LNb2, WtO, bo, Xk2, Xk2, M2_, D_, D_, D_/128);
  ln_bf_k<<<M2_, 256, 0, stream>>>(Xk2, ln_f_g, ln_f_b, LNb2);
  // H1 = gelu(LN @ W1 + b1)  (bf16 swizzled out, 128x64 tile -> 3072 blocks)
  gemm_bt_t<128,64,4,2, 1|2|4><<<((4*D_)/64) * (M2_/128), 256, 0, stream>>>(
      LNb2, Wt1, b1, nullptr, H1b, M2_, 4*D_, D_, (4*D_)/64);
  // T2 = h1 @ W2 + b2 + y  (fp32 out, bf16 res)
  gemm_bt_t<128,64,4,2, 8><<<(D_/64) * (M2_/128), 256, 0, stream>>>(
      H1b, Wt2, b2, Xk2, T2, M2_, D_, 4*D_, D_/64);
  final_ln_k<<<M2_, 256, 0, stream>>>(T2, tags, ln_s_g, ln_s_b, out);
}

// Round 11
// 323.045 us; speedup vs baseline: 1.2123x; 1.0630x over previous
//
#include <hip/hip_runtime.h>
#include <hip/hip_bf16.h>
#include <math.h>

#define B_    4
#define T_    1536
#define DIN_  512
#define D_    512
#define K_    2
#define H_    8
#define BAND_ 24
#define DH_   64
#define M_    (B_*T_)      // 6144 rows
#define M2_   (2*M_)       // both streams batched
#define ALPHA_ 6.0f
#define BETA_  0.5f
#define EPS_   1e-5f

using bf8  = __attribute__((ext_vector_type(8))) short;   // 8 bf16 (4 VGPRs)
using f32x4 = __attribute__((ext_vector_type(4))) float;  // 4 fp32 acc

__device__ __forceinline__ void async_copy16(const void* g, void* l) {
  __builtin_amdgcn_global_load_lds(
      (const __attribute__((address_space(1))) unsigned int*)g,
      (__attribute__((address_space(3))) unsigned int*)l, 16, 0, 0);
}

__device__ __forceinline__ short f2bf(float v) {
  __hip_bfloat16 h = (__hip_bfloat16)v;
  return *(short*)&h;
}
__device__ __forceinline__ float bf2f(short s) {
  union { unsigned u; float f; } c;
  c.u = ((unsigned)(unsigned short)s) << 16;
  return c.f;
}
// XOR-swizzle of 16B chunks within each 64-element column block (bank-conflict fix)
__device__ __forceinline__ int swz64(int row, int col) {
  return (col & ~63) | ((((col >> 3) ^ row) & 7) << 3) | (col & 7);
}
// tanh-form gelu, 7 VALU (2*log2e folded into polynomial), max err ~1e-3
__device__ __forceinline__ float fast_gelu(float x) {
  const float t = fmaf(0.1029504013f, x * x, 2.3021170686f);  // (a x^2 + b)*2*log2e
  const float e = __builtin_amdgcn_exp2f(x * t);              // e^{2u}
  const float r = __builtin_amdgcn_rcpf(e + 1.0f);
  return fmaf(-x, r, x);
}

// ---------------- bf16 MFMA GEMM: C = A[M,Kd] @ Bt[N,Kd]^T + bias (+res) (+gelu) (+tag)
// A and Bt chunk-swizzled. FLAGS (compile-time): 1=gelu, 2=bf16 out, 4=swizzled out,
// 8=bf16 residual, 16=fp32 residual, 32=add speaker tag (tag2[kk*N+col], kk=row>=M/2).
// 1-D grid, XCD-aware remap (gy % 8 == 0).
template<int BM, int BN, int NI, int NJ, int FLAGS>
__global__ __launch_bounds__(256) void gemm_bt_t(
    const short* __restrict__ A, const short* __restrict__ Bt,
    const float* __restrict__ bias, const void* __restrict__ res,
    const float* __restrict__ tag2,
    void* __restrict__ Cout, int M, int N, int Kd, int gx) {
  __shared__ short lA[BM * 64];
  __shared__ short lB[BN * 64];
  const int gy   = gridDim.x / gx;
  const int xcd  = blockIdx.x & 7;
  const int seq  = blockIdx.x >> 3;
  const int rpx  = gy >> 3;                 // row-tiles per XCD
  const int by   = xcd * rpx + seq / gx;
  const int bx   = seq % gx;
  const int tid  = threadIdx.x;
  const int wave = tid >> 6, lane = tid & 63;
  const int block_m = by * BM, block_n = bx * BN;
  const int wm = (wave & 1) * (BM / 2), wn = (wave >> 1) * (BN / 2);
  const int l15 = lane & 15, quad = lane >> 4, l7 = lane & 7;
  f32x4 acc[NI][NJ] = {};

  for (int k0 = 0; k0 < Kd; k0 += 64) {
    __syncthreads();               // previous tile's LDS reads complete
#pragma unroll
    for (int i = 0; i < BM / 32; ++i) {
      const int cb = wave * (BM * 2) + i * 64;
      const int c  = cb + lane;                 // chunk of 8 bf16
      async_copy16(A + (size_t)(block_m + (c >> 3)) * Kd + k0 + (c & 7) * 8,
                   &lA[cb * 8]);
    }
#pragma unroll
    for (int i = 0; i < BN / 32; ++i) {
      const int cb = wave * (BN * 2) + i * 64;
      const int c  = cb + lane;
      async_copy16(Bt + (size_t)(block_n + (c >> 3)) * Kd + k0 + (c & 7) * 8,
                   &lB[cb * 8]);
    }
    __syncthreads();               // barrier drains vmcnt => LDS tiles ready
#pragma unroll
    for (int ks = 0; ks < 2; ++ks) {
      bf8 af[NI], bfr[NJ];
#pragma unroll
      for (int i = 0; i < NI; ++i)
        af[i] = *(const bf8*)&lA[(wm + i * 16 + l15) * 64 + (((ks * 4 + quad) ^ l7) << 3)];
#pragma unroll
      for (int j = 0; j < NJ; ++j)
        bfr[j] = *(const bf8*)&lB[(wn + j * 16 + l15) * 64 + (((ks * 4 + quad) ^ l7) << 3)];
#pragma unroll
      for (int i = 0; i < NI; ++i)
#pragma unroll
        for (int j = 0; j < NJ; ++j)
          acc[i][j] = __builtin_amdgcn_mfma_f32_16x16x32_bf16(af[i], bfr[j], acc[i][j], 0, 0, 0);
    }
  }

  const int half = M >> 1;
#pragma unroll
  for (int i = 0; i < NI; ++i) {
    const int mbase = block_m + wm + i * 16 + (lane >> 4) * 4;
#pragma unroll
    for (int j = 0; j < NJ; ++j) {
      const int col = block_n + wn + j * 16 + l15;
      const float bb = bias[col];
#pragma unroll
      for (int r = 0; r < 4; ++r) {
        const int row = mbase + r;
        const size_t idx = (size_t)row * N + col;
        float v = acc[i][j][r] + bb;
        if constexpr (FLAGS & 8)  v += bf2f(((const short*)res)[idx]);
        if constexpr (FLAGS & 16) v += ((const float*)res)[idx];
        if constexpr (FLAGS & 32) v += tag2[(row >= half ? N : 0) + col];
        if constexpr (FLAGS & 1)  v = fast_gelu(v);
        if constexpr (FLAGS & 2) {
          const int oc = (FLAGS & 4) ? swz64(row, col) : col;
          ((short*)Cout)[(size_t)row * N + oc] = f2bf(v);
        } else {
          ((float*)Cout)[idx] = v;
        }
      }
    }
  }
}

// ---------------- merged prep: x_m cast (swizzled) + 7 weight transposes + bias concat
__device__ __forceinline__ void tconv_tile(const float* __restrict__ W,
                                           short* __restrict__ Wt, int K, int N,
                                           int bx, int by, int tid, float (*s)[33]) {
  const int tx = tid & 31, ty = tid >> 5;
  const int k0 = by * 32, n0 = bx * 32;
#pragma unroll
  for (int r = 0; r < 4; ++r)
    s[ty * 4 + r][tx] = W[(size_t)(k0 + ty * 4 + r) * N + n0 + tx];
  __syncthreads();
#pragma unroll
  for (int r = 0; r < 4; ++r) {
    const int n = n0 + ty * 4 + r;
    Wt[(size_t)n * K + swz64(n, k0 + tx)] = f2bf(s[tx][ty * 4 + r]);
  }
}

__global__ __launch_bounds__(256) void prep_k(
    const float* __restrict__ x_m, short* __restrict__ xb,
    const float* __restrict__ W_in, short* __restrict__ WtIn,
    const float* __restrict__ Wq,  short* __restrict__ WtQ,
    const float* __restrict__ Wk,  const float* __restrict__ Wv,
    short* __restrict__ WtKV,
    const float* __restrict__ Wo,  short* __restrict__ WtO,
    const float* __restrict__ W1,  short* __restrict__ Wt1,
    const float* __restrict__ W2,  short* __restrict__ Wt2,
    const float* __restrict__ bk,  const float* __restrict__ bv,
    float* __restrict__ bkv) {
  __shared__ float s[32][33];
  const int blk = blockIdx.x, tid = threadIdx.x;
  if (blk < 3072) {                       // x_m -> bf16 swizzled (float4 per thread)
    const int e = (blk * 256 + tid) * 4;
    const int row = e >> 9, col = e & 511;
    const float4 v = *(const float4*)&x_m[e];
    short4 o;
    o.x = f2bf(v.x); o.y = f2bf(v.y); o.z = f2bf(v.z); o.w = f2bf(v.w);
    *(short4*)&xb[((size_t)row << 9) | swz64(row, col)] = o;
  } else if (blk < 3328) {                // W_in [512,512]
    const int t = blk - 3072; tconv_tile(W_in, WtIn, DIN_, D_, t & 15, t >> 4, tid, s);
  } else if (blk < 3584) {                // Wq
    const int t = blk - 3328; tconv_tile(Wq, WtQ, D_, D_, t & 15, t >> 4, tid, s);
  } else if (blk < 3840) {                // Wk -> WtKV[0:512]
    const int t = blk - 3584; tconv_tile(Wk, WtKV, D_, D_, t & 15, t >> 4, tid, s);
  } else if (blk < 4096) {                // Wv -> WtKV[512:1024]
    const int t = blk - 3840; tconv_tile(Wv, WtKV + (size_t)D_ * D_, D_, D_, t & 15, t >> 4, tid, s);
  } else if (blk < 4352) {                // Wo
    const int t = blk - 4096; tconv_tile(Wo, WtO, D_, D_, t & 15, t >> 4, tid, s);
  } else if (blk < 5376) {                // W1 [512,2048]: gx=64
    const int t = blk - 4352; tconv_tile(W1, Wt1, D_, 4 * D_, t & 63, t >> 6, tid, s);
  } else if (blk < 6400) {                // W2 [2048,512]: gx=16
    const int t = blk - 5376; tconv_tile(W2, Wt2, 4 * D_, D_, t & 15, t >> 4, tid, s);
  } else {                                // bias concat (4 blocks)
    const int i = (blk - 6400) * 256 + tid;
    bkv[i] = (i < D_) ? bk[i] : bv[i - D_];
  }
}

// ---------------- block reduction helper (256 threads)
__device__ __forceinline__ float block_sum(float s, float* red, int tid) {
  red[tid] = s; __syncthreads();
  for (int o = 128; o > 0; o >>= 1) {
    if (tid < o) red[tid] += red[tid + o];
    __syncthreads();
  }
  float r = red[0];
  __syncthreads();
  return r;
}

// ---------------- LayerNorm, bf16 in: out(bf16, swizzled) = LN(in) * g + b
__global__ __launch_bounds__(256) void ln_bf_k(const short* __restrict__ in,
                                               const float* __restrict__ g,
                                               const float* __restrict__ b,
                                               short* __restrict__ out) {
  __shared__ float red[256];
  const int row = blockIdx.x, tid = threadIdx.x;
  const short2 xv = *(const short2*)&in[(size_t)row * D_ + 2 * tid];
  const float v0 = bf2f(xv.x), v1 = bf2f(xv.y);
  const float mean = block_sum(v0 + v1, red, tid) * (1.0f / D_);
  const float d0 = v0 - mean, d1 = v1 - mean;
  const float var = block_sum(d0 * d0 + d1 * d1, red, tid) * (1.0f / D_);
  const float inv = rsqrtf(var + EPS_);
  const float2 gg = *(const float2*)&g[2 * tid];
  const float2 bb = *(const float2*)&b[2 * tid];
  short2 o;
  o.x = f2bf(d0 * inv * gg.x + bb.x);
  o.y = f2bf(d1 * inv * gg.y + bb.y);
  *(short2*)&out[(size_t)row * D_ + swz64(row, 2 * tid)] = o;
}

// ---------------- gate + LN, both streams (X bf16 in): Xk(bf16) ; LN out swizzled bf16
__global__ __launch_bounds__(256) void scale_ln_k(
    const short* __restrict__ X, const float* __restrict__ Ain,
    const float* __restrict__ g, const float* __restrict__ b,
    short* __restrict__ Xk, short* __restrict__ out) {
  __shared__ float red[256];
  const int row = blockIdx.x, tid = threadIdx.x;
  const int kk = row / M_, rm = row % M_;
  const float a = Ain[(size_t)rm * K_ + kk];
  const float w = __builtin_amdgcn_rcpf(1.0f + __expf(-ALPHA_ * (a - BETA_)));
  const short2 xv = *(const short2*)&X[(size_t)rm * D_ + 2 * tid];
  const float v0 = bf2f(xv.x) * w, v1 = bf2f(xv.y) * w;
  short2 xo; xo.x = f2bf(v0); xo.y = f2bf(v1);
  *(short2*)&Xk[(size_t)row * D_ + 2 * tid] = xo;
  const float mean = block_sum(v0 + v1, red, tid) * (1.0f / D_);
  const float d0 = v0 - mean, d1 = v1 - mean;
  const float var = block_sum(d0 * d0 + d1 * d1, red, tid) * (1.0f / D_);
  const float inv = rsqrtf(var + EPS_);
  const float2 gg = *(const float2*)&g[2 * tid];
  const float2 bb = *(const float2*)&b[2 * tid];
  short2 o;
  o.x = f2bf(d0 * inv * gg.x + bb.x);
  o.y = f2bf(d1 * inv * gg.y + bb.y);
  *(short2*)&out[(size_t)row * D_ + swz64(row, 2 * tid)] = o;
}

// ---------------- final LN: in = T2b (y+h2+tag, bf16); scatter to concat layout (fp32)
__global__ __launch_bounds__(256) void final_ln_k(
    const short* __restrict__ t2, const float* __restrict__ g,
    const float* __restrict__ b, float* __restrict__ out) {
  __shared__ float red[256];
  const int row = blockIdx.x, tid = threadIdx.x;
  const int kk = row / M_, rm = row % M_;
  const int bb_ = rm / T_, t = rm % T_;
  const size_t orow = (size_t)bb_ * (K_ * T_) + (size_t)kk * T_ + t;
  const short2 xv = *(const short2*)&t2[(size_t)row * D_ + 2 * tid];
  const float v0 = bf2f(xv.x), v1 = bf2f(xv.y);
  const float mean = block_sum(v0 + v1, red, tid) * (1.0f / D_);
  const float d0 = v0 - mean, d1 = v1 - mean;
  const float var = block_sum(d0 * d0 + d1 * d1, red, tid) * (1.0f / D_);
  const float inv = rsqrtf(var + EPS_);
  const float2 gg = *(const float2*)&g[2 * tid];
  const float2 bb = *(const float2*)&b[2 * tid];
  float2 o;
  o.x = d0 * inv * gg.x + bb.x;
  o.y = d1 * inv * gg.y + bb.y;
  *(float2*)&out[orow * D_ + 2 * tid] = o;
}

// ---------------- MFMA banded attention, both streams
// q [2M,D] bf16 (unswizzled); KVp [M,2D] bf16 (unswizzled); out bf16 swizzled
#define QT_  64
#define KT_  (QT_ + 2 * BAND_)   // 112 rows
#define SKQ_ 72                  // row stride (shorts) for sK/sQ/sP
#define STV_ 136                 // row stride (shorts) for sVt
__global__ __launch_bounds__(256) void attn_mfma_k(
    const short* __restrict__ q, const short* __restrict__ KVp,
    short* __restrict__ out) {
  __shared__ short sK[KT_ * SKQ_];
  __shared__ short sQ[QT_ * SKQ_];
  __shared__ short sVt[DH_ * STV_];     // transposed: [dim][key row]
  __shared__ short sP[4][16 * SKQ_];
  const int t0 = blockIdx.x * QT_;
  const int h  = blockIdx.y;
  const int z  = blockIdx.z;            // kk*B + b
  const int b  = z % B_;
  const int tid = threadIdx.x;
  const int wave = tid >> 6, lane = tid & 63;
  const int rr = tid >> 5, c2 = tid & 31;

  for (int r0 = 0; r0 < KT_; r0 += 8) {
    const int r = r0 + rr;
    const int s = t0 - BAND_ + r;
    short2 kv = {0, 0}, vv = {0, 0};
    if (s >= 0 && s < T_) {
      const size_t g = (size_t)(b * T_ + s) * (2 * D_) + h * DH_ + c2 * 2;
      kv = *(const short2*)&KVp[g];
      vv = *(const short2*)&KVp[g + D_];
    }
    *(short2*)&sK[r * SKQ_ + c2 * 2] = kv;
    sVt[(c2 * 2)     * STV_ + r] = vv.x;
    sVt[(c2 * 2 + 1) * STV_ + r] = vv.y;
  }
  for (int r0 = 0; r0 < QT_; r0 += 8) {
    const int r = r0 + rr;
    const size_t g = (size_t)(z * T_ + t0 + r) * D_ + h * DH_ + c2 * 2;
    *(short2*)&sQ[r * SKQ_ + c2 * 2] = *(const short2*)&q[g];
  }
  __syncthreads();

  const int qg  = wave * 16;            // query group base (also key window base)
  const int l15 = lane & 15, quad = lane >> 4;

  // ---- S = Q16x64 @ K64x64^T  (8 MFMAs)
  bf8 qa0 = *(const bf8*)&sQ[(qg + l15) * SKQ_ + quad * 8];
  bf8 qa1 = *(const bf8*)&sQ[(qg + l15) * SKQ_ + 32 + quad * 8];
  f32x4 acc[4];
#pragma unroll
  for (int j = 0; j < 4; ++j) {
    const bf8 kb0 = *(const bf8*)&sK[(qg + j * 16 + l15) * SKQ_ + quad * 8];
    const bf8 kb1 = *(const bf8*)&sK[(qg + j * 16 + l15) * SKQ_ + 32 + quad * 8];
    f32x4 z4 = {0.f, 0.f, 0.f, 0.f};
    acc[j] = __builtin_amdgcn_mfma_f32_16x16x32_bf16(qa0, kb0, z4, 0, 0, 0);
    acc[j] = __builtin_amdgcn_mfma_f32_16x16x32_bf16(qa1, kb1, acc[j], 0, 0, 0);
  }

  // ---- banded softmax on C-layout rows (row = quad*4+reg, col = j*16+l15)
#pragma unroll
  for (int reg = 0; reg < 4; ++reg) {
    const int i = quad * 4 + reg;       // query within group
    float sc[4];
    float mx = -1e30f;
#pragma unroll
    for (int j = 0; j < 4; ++j) {
      const int c = j * 16 + l15;       // key within 64-window
      const int s = t0 + qg - BAND_ + c;
      const int rel = c - i;            // in [0,48] when inside band
      const bool valid = (rel >= 0) && (rel <= 2 * BAND_) && (s >= 0) && (s < T_);
      sc[j] = valid ? acc[j][reg] * 0.125f : -1e30f;
      mx = fmaxf(mx, sc[j]);
    }
    for (int o = 1; o < 16; o <<= 1) mx = fmaxf(mx, __shfl_xor(mx, o));
    float p[4], se = 0.0f;
#pragma unroll
    for (int j = 0; j < 4; ++j) {
      p[j] = (sc[j] > -1e29f) ? __expf(sc[j] - mx) : 0.0f;
      se += p[j];
    }
    for (int o = 1; o < 16; o <<= 1) se += __shfl_xor(se, o);
    const float inv = __builtin_amdgcn_rcpf(se);
#pragma unroll
    for (int j = 0; j < 4; ++j)
      sP[wave][i * SKQ_ + j * 16 + l15] = f2bf(p[j] * inv);
  }

  // ---- O = P16x64 @ V64x64  (8 MFMAs; V from transposed LDS)
  const bf8 pa0 = *(const bf8*)&sP[wave][l15 * SKQ_ + quad * 8];
  const bf8 pa1 = *(const bf8*)&sP[wave][l15 * SKQ_ + 32 + quad * 8];
  f32x4 oacc[4] = {};
#pragma unroll
  for (int dt = 0; dt < 4; ++dt) {
    const bf8 vb0 = *(const bf8*)&sVt[(dt * 16 + l15) * STV_ + qg + quad * 8];
    const bf8 vb1 = *(const bf8*)&sVt[(dt * 16 + l15) * STV_ + qg + 32 + quad * 8];
    oacc[dt] = __builtin_amdgcn_mfma_f32_16x16x32_bf16(pa0, vb0, oacc[dt], 0, 0, 0);
    oacc[dt] = __builtin_amdgcn_mfma_f32_16x16x32_bf16(pa1, vb1, oacc[dt], 0, 0, 0);
  }
#pragma unroll
  for (int dt = 0; dt < 4; ++dt)
#pragma unroll
    for (int reg = 0; reg < 4; ++reg) {
      const int i = quad * 4 + reg;
      const int row = t0 + qg + i;
      const int col = h * DH_ + dt * 16 + l15;
      out[(size_t)(z * T_ + row) * D_ + swz64(row, col)] = f2bf(oacc[dt][reg]);
    }
}

extern "C" void kernel_launch(void* const* d_in, const int* in_sizes, int n_in,
                              void* d_out, int out_size, void* d_ws, size_t ws_size,
                              hipStream_t stream) {
  const float* x_m    = (const float*)d_in[0];
  const float* A      = (const float*)d_in[1];
  const float* W_in   = (const float*)d_in[2];
  const float* b_in   = (const float*)d_in[3];
  const float* ln_q_g = (const float*)d_in[4];
  const float* ln_q_b = (const float*)d_in[5];
  const float* ln_kv_g= (const float*)d_in[6];
  const float* ln_kv_b= (const float*)d_in[7];
  const float* Wq     = (const float*)d_in[8];
  const float* bq     = (const float*)d_in[9];
  const float* Wk     = (const float*)d_in[10];
  const float* bk     = (const float*)d_in[11];
  const float* Wv     = (const float*)d_in[12];
  const float* bv     = (const float*)d_in[13];
  const float* Wo     = (const float*)d_in[14];
  const float* bo     = (const float*)d_in[15];
  const float* ln_f_g = (const float*)d_in[16];
  const float* ln_f_b = (const float*)d_in[17];
  const float* W1     = (const float*)d_in[18];
  const float* b1     = (const float*)d_in[19];
  const float* W2     = (const float*)d_in[20];
  const float* b2     = (const float*)d_in[21];
  const float* ln_s_g = (const float*)d_in[22];
  const float* ln_s_b = (const float*)d_in[23];
  const float* tags   = (const float*)d_in[24];
  float* out = (float*)d_out;

  const size_t MD = (size_t)M_ * D_;
  // fp32 buffers
  float* bkv = (float*)d_ws;           // [1024]
  // bf16 buffers
  short* X    = (short*)(bkv + 1024);  // [M,D]  unswizzled
  short* Xk2  = X    + MD;             // [2M,D] gated X, then y (bf16, unswizzled)
  short* LNb2 = Xk2  + 2 * MD;         // [2M,D]; first MD also = KV LN (swizzled)
  short* qb2  = LNb2 + 2 * MD;         // [2M,D]; first MD also = xb (x_m bf16 swz)
  short* KVpb = qb2  + 2 * MD;         // [M,2D] interleaved K|V (unswizzled)
  short* T2b  = KVpb + 2 * MD;         // [2M,D] y+h2+tag (bf16)
  short* H1b  = T2b  + 2 * MD;         // [2M,4D] swizzled
  short* WtIn = H1b + (size_t)M2_ * 4 * D_;
  short* WtQ  = WtIn + (size_t)D_ * DIN_;
  short* WtKV = WtQ  + (size_t)D_ * D_;        // [2D, D]
  short* WtO  = WtKV + (size_t)2 * D_ * D_;
  short* Wt1  = WtO  + (size_t)D_ * D_;        // [4D, D]
  short* Wt2  = Wt1  + (size_t)4 * D_ * D_;    // [D, 4D]
  short* xb   = qb2;                   // alias (used before Q GEMM)
  short* KVb  = LNb2;                  // alias (used before scale_ln)

  // ---- merged prep: x_m cast + 7 weight transposes + K/V bias concat (1 launch)
  prep_k<<<6404, 256, 0, stream>>>(x_m, xb, W_in, WtIn, Wq, WtQ, Wk, Wv, WtKV,
                                   Wo, WtO, W1, Wt1, W2, Wt2, bk, bv, bkv);

  // X = x_m @ W_in + b_in  (bf16 unswizzled out)
  gemm_bt_t<128,64,4,2, 2><<<(D_/64) * (M_/128), 256, 0, stream>>>(
      xb, WtIn, b_in, nullptr, nullptr, X, M_, D_, DIN_, D_/64);
  // KVb = LN(X)  (swizzled bf16)
  ln_bf_k<<<M_, 256, 0, stream>>>(X, ln_kv_g, ln_kv_b, KVb);
  // K|V projection, N=1024 (bf16 out, UNswizzled: consumed by attention)
  gemm_bt_t<128,128,4,4, 2><<<((2*D_)/128) * (M_/128), 256, 0, stream>>>(
      KVb, WtKV, bkv, nullptr, nullptr, KVpb, M_, 2*D_, D_, (2*D_)/128);

  // ---- both streams batched over 2M rows
  scale_ln_k<<<M2_, 256, 0, stream>>>(X, A, ln_q_g, ln_q_b, Xk2, LNb2);
  gemm_bt_t<128,128,4,4, 2><<<(D_/128) * (M2_/128), 256, 0, stream>>>(
      LNb2, WtQ, bq, nullptr, nullptr, qb2, M2_, D_, D_, D_/128);  // q: unswizzled
  attn_mfma_k<<<dim3(T_/QT_, H_, B_*K_), 256, 0, stream>>>(qb2, KVpb, LNb2);
  // y = attn @ Wo + bo + Xk  (bf16 in-place, bf16 res)
  gemm_bt_t<128,128,4,4, 2|8><<<(D_/128) * (M2_/128), 256, 0, stream>>>(
      LNb2, WtO, bo, Xk2, nullptr, Xk2, M2_, D_, D_, D_/128);
  ln_bf_k<<<M2_, 256, 0, stream>>>(Xk2, ln_f_g, ln_f_b, LNb2);
  // H1 = gelu(LN @ W1 + b1)  (bf16 swizzled out, 128x64 tile -> 3072 blocks)
  gemm_bt_t<128,64,4,2, 1|2|4><<<((4*D_)/64) * (M2_/128), 256, 0, stream>>>(
      LNb2, Wt1, b1, nullptr, nullptr, H1b, M2_, 4*D_, D_, (4*D_)/64);
  // T2b = h1 @ W2 + b2 + y + tag  (bf16 out, bf16 res, tag fused)
  gemm_bt_t<128,64,4,2, 2|8|32><<<(D_/64) * (M2_/128), 256, 0, stream>>>(
      H1b, Wt2, b2, Xk2, tags, T2b, M2_, D_, 4*D_, D_/64);
  final_ln_k<<<M2_, 256, 0, stream>>>(T2b, ln_s_g, ln_s_b, out);
}